// Round 1
// baseline (823.610 us; speedup 1.0000x reference)
//
#include <hip/hip_runtime.h>

typedef __bf16 bf16_t;
typedef __attribute__((ext_vector_type(8))) __bf16 bf16x8;
typedef __attribute__((ext_vector_type(4))) __bf16 bf16x4;
typedef __attribute__((ext_vector_type(4))) float f32x4;

static constexpr int kB = 2, kT = 2048, kS = 576, kC = 1024, kH = 16, kD = 64;

#define MFMA16(a, b, c) __builtin_amdgcn_mfma_f32_16x16x32_bf16((a), (b), (c), 0, 0, 0)

__device__ __forceinline__ void gld_lds16(const bf16_t* g, bf16_t* l) {
    __builtin_amdgcn_global_load_lds((const __attribute__((address_space(1))) unsigned int*)g,
                                     (__attribute__((address_space(3))) unsigned int*)l, 16, 0, 0);
}

__device__ inline float gelu_tanh(float x) {
    float u = 1.5957691216057308f * (x + 0.044715f * x * x * x);
    float t = 1.f - 2.f / (__expf(u) + 1.f);
    return 0.5f * x * (1.f + t);
}

// ---------------- weight transpose + f32->bf16: W[K,N] -> WT[N,K] ----------------
__global__ void transpose_w(const float* __restrict__ W, bf16_t* __restrict__ WT, int K, int N) {
    __shared__ float tile[32][33];
    int n0 = blockIdx.x * 32, k0 = blockIdx.y * 32;
    int tx = threadIdx.x, ty = threadIdx.y;
#pragma unroll
    for (int i = 0; i < 4; ++i)
        tile[ty + i * 8][tx] = W[(size_t)(k0 + ty + i * 8) * N + n0 + tx];
    __syncthreads();
#pragma unroll
    for (int i = 0; i < 4; ++i)
        WT[(size_t)(n0 + ty + i * 8) * K + k0 + tx] = (bf16_t)tile[tx][ty + i * 8];
}

// ---------------- f32 -> bf16 elementwise (n4 = count/4) ----------------
__global__ void f32_to_bf16(const float* __restrict__ in, bf16_t* __restrict__ out, int n4) {
    int i = blockIdx.x * 256 + threadIdx.x;
    if (i < n4) {
        float4 v = ((const float4*)in)[i];
        bf16x4 o;
        o[0] = (bf16_t)v.x; o[1] = (bf16_t)v.y; o[2] = (bf16_t)v.z; o[3] = (bf16_t)v.w;
        ((bf16x4*)out)[i] = o;
    }
}

// ---------------- f32 copy (split-K accumulator init with residual) ----------------
__global__ void copy_f32(const float* __restrict__ in, float* __restrict__ out, int n4) {
    int i = blockIdx.x * 256 + threadIdx.x;
    if (i < n4) ((float4*)out)[i] = ((const float4*)in)[i];
}

// ---------------- LayerNorm: fp32 in [rows, 1024] -> bf16 out ----------------
__global__ __launch_bounds__(256) void ln_kernel(const float* __restrict__ x,
                                                 const float* __restrict__ w,
                                                 const float* __restrict__ bb,
                                                 bf16_t* __restrict__ out) {
    int row = blockIdx.x, tid = threadIdx.x;
    const float* xr = x + (size_t)row * kC;
    float4 v = ((const float4*)xr)[tid];
    float s1 = v.x + v.y + v.z + v.w;
    float s2 = v.x * v.x + v.y * v.y + v.z * v.z + v.w * v.w;
#pragma unroll
    for (int o = 32; o > 0; o >>= 1) {
        s1 += __shfl_down(s1, o);
        s2 += __shfl_down(s2, o);
    }
    __shared__ float red[8];
    __shared__ float mv[2];
    int wid = tid >> 6, lane = tid & 63;
    if (lane == 0) { red[wid] = s1; red[4 + wid] = s2; }
    __syncthreads();
    if (tid == 0) {
        float a = red[0] + red[1] + red[2] + red[3];
        float c = red[4] + red[5] + red[6] + red[7];
        float mean = a * (1.f / kC);
        float var = c * (1.f / kC) - mean * mean;
        mv[0] = mean;
        mv[1] = rsqrtf(var + 1e-5f);
    }
    __syncthreads();
    float mean = mv[0], rstd = mv[1];
    float4 wv = ((const float4*)w)[tid];
    float4 bv = ((const float4*)bb)[tid];
    bf16x4 o4;
    o4[0] = (bf16_t)((v.x - mean) * rstd * wv.x + bv.x);
    o4[1] = (bf16_t)((v.y - mean) * rstd * wv.y + bv.y);
    o4[2] = (bf16_t)((v.z - mean) * rstd * wv.z + bv.z);
    o4[3] = (bf16_t)((v.w - mean) * rstd * wv.w + bv.w);
    *(bf16x4*)&out[(size_t)row * kC + tid * 4] = o4;
}

// ---------------- m97-style GEMM: C[M,N] = A[M,K] @ WT[N,K]^T (+epilogue) ----------------
// EPI: 0 bf16+bias, 1 f32 = acc+bias+res, 2 bf16 gelu(acc+bias), 4 qkv-split (Out=q,Out2=k,Out3=vT)
template <int EPI, int BM>
__global__ __launch_bounds__(256) void gemm128(const bf16_t* __restrict__ A, const bf16_t* __restrict__ Bw,
                                               const float* __restrict__ bias, const float* __restrict__ res,
                                               void* __restrict__ Out, void* __restrict__ Out2,
                                               void* __restrict__ Out3, int M, int N, int K, int lda, int ldb,
                                               int ldc) {
    constexpr int MT = BM / 32;
    __shared__ __align__(16) bf16_t As[BM * 64];
    __shared__ __align__(16) bf16_t Bs[128 * 64];
    const int tid = threadIdx.x;
    const int m0 = blockIdx.y * BM, n0 = blockIdx.x * 128;
    const int lane = tid & 63, wid = tid >> 6;
    const int l16 = lane & 15, quad = lane >> 4;
    const int wm = (wid >> 1) * (BM / 2), wn = (wid & 1) * 64;
    f32x4 acc[MT][4] = {};

    const bf16_t* Ab = A + (size_t)m0 * lda;
    const bf16_t* Bb = Bw + (size_t)n0 * ldb;

    for (int k0 = 0; k0 < K; k0 += 64) {
        __syncthreads();
#pragma unroll
        for (int i = 0; i < BM / 32; ++i) {
            int chunk = tid + i * 256;
            int row = chunk >> 3, col = (chunk & 7) * 8;
            gld_lds16(Ab + (size_t)row * lda + k0 + col, As + row * 64 + col);
        }
#pragma unroll
        for (int i = 0; i < 4; ++i) {
            int chunk = tid + i * 256;
            int row = chunk >> 3, col = (chunk & 7) * 8;
            gld_lds16(Bb + (size_t)row * ldb + k0 + col, Bs + row * 64 + col);
        }
        __syncthreads();
#pragma unroll
        for (int kk = 0; kk < 64; kk += 32) {
            bf16x8 af[MT], bw[4];
#pragma unroll
            for (int mt = 0; mt < MT; ++mt)
                af[mt] = *(const bf16x8*)&As[(wm + mt * 16 + l16) * 64 + kk + quad * 8];
#pragma unroll
            for (int nt = 0; nt < 4; ++nt)
                bw[nt] = *(const bf16x8*)&Bs[(wn + nt * 16 + l16) * 64 + kk + quad * 8];
#pragma unroll
            for (int mt = 0; mt < MT; ++mt)
#pragma unroll
                for (int nt = 0; nt < 4; ++nt) acc[mt][nt] = MFMA16(af[mt], bw[nt], acc[mt][nt]);
        }
    }

#pragma unroll
    for (int mt = 0; mt < MT; ++mt)
#pragma unroll
        for (int nt = 0; nt < 4; ++nt) {
            int n = n0 + wn + nt * 16 + l16;
            float bv = bias ? bias[n] : 0.f;
#pragma unroll
            for (int r = 0; r < 4; ++r) {
                int m = m0 + wm + mt * 16 + quad * 4 + r;
                float v = acc[mt][nt][r] + bv;
                if constexpr (EPI == 2) v = gelu_tanh(v);
                if constexpr (EPI == 0 || EPI == 2) {
                    ((bf16_t*)Out)[(size_t)m * ldc + n] = (bf16_t)v;
                } else if constexpr (EPI == 1) {
                    ((float*)Out)[(size_t)m * ldc + n] = v + res[(size_t)m * ldc + n];
                } else { // EPI 4: qkv split
                    int b = m >> 11, t = m & 2047;
                    if (n < 2048) {
                        int h = (n & 1023) >> 6, d = n & 63;
                        bf16_t* dst = (n < 1024) ? (bf16_t*)Out : (bf16_t*)Out2;
                        dst[(((size_t)b * kH + h) * kT + t) * kD + d] = (bf16_t)v;
                    } else {
                        int n2 = n - 2048;
                        int h = n2 >> 6, d = n2 & 63;
                        ((bf16_t*)Out3)[(((size_t)b * kH + h) * kD + d) * kT + t] = (bf16_t)v;
                    }
                }
            }
        }
}

// ---------------- split-K GEMM: Out[M,N] += A[M,K] @ WT[N,K]^T (+bias on z==0) ----------------
// Out must be pre-initialized (with residual) before launch. blockIdx.z picks the K-chunk.
template <int BM>
__global__ __launch_bounds__(256) void gemm_sk(const bf16_t* __restrict__ A, const bf16_t* __restrict__ Bw,
                                               const float* __restrict__ bias, float* __restrict__ Out,
                                               int Kchunk, int lda, int ldb, int ldc) {
    constexpr int MT = BM / 32;
    __shared__ __align__(16) bf16_t As[BM * 64];
    __shared__ __align__(16) bf16_t Bs[128 * 64];
    const int tid = threadIdx.x;
    const int m0 = blockIdx.y * BM, n0 = blockIdx.x * 128;
    const int lane = tid & 63, wid = tid >> 6;
    const int l16 = lane & 15, quad = lane >> 4;
    const int wm = (wid >> 1) * (BM / 2), wn = (wid & 1) * 64;
    f32x4 acc[MT][4] = {};

    const bf16_t* Ab = A + (size_t)m0 * lda;
    const bf16_t* Bb = Bw + (size_t)n0 * ldb;
    const int kbase = blockIdx.z * Kchunk;

    for (int k0 = kbase; k0 < kbase + Kchunk; k0 += 64) {
        __syncthreads();
#pragma unroll
        for (int i = 0; i < BM / 32; ++i) {
            int chunk = tid + i * 256;
            int row = chunk >> 3, col = (chunk & 7) * 8;
            gld_lds16(Ab + (size_t)row * lda + k0 + col, As + row * 64 + col);
        }
#pragma unroll
        for (int i = 0; i < 4; ++i) {
            int chunk = tid + i * 256;
            int row = chunk >> 3, col = (chunk & 7) * 8;
            gld_lds16(Bb + (size_t)row * ldb + k0 + col, Bs + row * 64 + col);
        }
        __syncthreads();
#pragma unroll
        for (int kk = 0; kk < 64; kk += 32) {
            bf16x8 af[MT], bw[4];
#pragma unroll
            for (int mt = 0; mt < MT; ++mt)
                af[mt] = *(const bf16x8*)&As[(wm + mt * 16 + l16) * 64 + kk + quad * 8];
#pragma unroll
            for (int nt = 0; nt < 4; ++nt)
                bw[nt] = *(const bf16x8*)&Bs[(wn + nt * 16 + l16) * 64 + kk + quad * 8];
#pragma unroll
            for (int mt = 0; mt < MT; ++mt)
#pragma unroll
                for (int nt = 0; nt < 4; ++nt) acc[mt][nt] = MFMA16(af[mt], bw[nt], acc[mt][nt]);
        }
    }

    const bool addb = (blockIdx.z == 0);
#pragma unroll
    for (int mt = 0; mt < MT; ++mt)
#pragma unroll
        for (int nt = 0; nt < 4; ++nt) {
            int n = n0 + wn + nt * 16 + l16;
            float bv = addb ? bias[n] : 0.f;
#pragma unroll
            for (int r = 0; r < 4; ++r) {
                int m = m0 + wm + mt * 16 + quad * 4 + r;
                atomicAdd(&Out[(size_t)m * ldc + n], acc[mt][nt][r] + bv);
            }
        }
}

// ---------------- flash causal self-attention v3 (no-max softmax) ----------------
// q,k: [b,h,t,d] bf16; vT: [b,h,d,t] bf16; sa out: [b,t,c] bf16
__global__ __launch_bounds__(256) void flash_self3(const bf16_t* __restrict__ qb, const bf16_t* __restrict__ kb,
                                                   const bf16_t* __restrict__ vT, bf16_t* __restrict__ sa) {
    const int tid = threadIdx.x;
    const int qi = gridDim.x - 1 - blockIdx.x; // heavy blocks first
    const int h = blockIdx.y, b = blockIdx.z;
    const int lane = tid & 63, wid = tid >> 6;
    const int l16 = lane & 15, quad = lane >> 4;
    const size_t bh = (size_t)b * kH + h;

    __shared__ __align__(16) bf16_t Qs[64 * 64];
    __shared__ __align__(16) bf16_t Ks[64 * 64];
    __shared__ __align__(16) bf16_t VTs[64 * 64];
    bf16_t* Ps = Qs; // reuse after Q frags are hoisted

    const bf16_t* qsrc = qb + (bh * kT + (size_t)qi * 64) * kD;
#pragma unroll
    for (int i = 0; i < 2; ++i) {
        int chunk = tid + i * 256;
        gld_lds16(qsrc + chunk * 8, Qs + chunk * 8);
    }
    __syncthreads();
    bf16x8 aq[2];
    aq[0] = *(const bf16x8*)&Qs[(wid * 16 + l16) * 64 + quad * 8];
    aq[1] = *(const bf16x8*)&Qs[(wid * 16 + l16) * 64 + 32 + quad * 8];
#pragma unroll
    for (int j = 0; j < 8; ++j) { aq[0][j] *= (bf16_t)0.125f; aq[1][j] *= (bf16_t)0.125f; } // exact pow2

    f32x4 o[4] = {};
    float lsum[4] = {0.f, 0.f, 0.f, 0.f};
    const int qrow = qi * 64 + wid * 16 + quad * 4;

    for (int kt = 0; kt <= qi; ++kt) {
        __syncthreads();
        const bf16_t* ksrc = kb + (bh * kT + (size_t)kt * 64) * kD;
        const bf16_t* vsrc = vT + bh * kD * kT + (size_t)kt * 64;
#pragma unroll
        for (int i = 0; i < 2; ++i) {
            int chunk = tid + i * 256;
            gld_lds16(ksrc + chunk * 8, Ks + chunk * 8);
            int row = chunk >> 3, col = (chunk & 7) * 8;
            gld_lds16(vsrc + (size_t)row * kT + col, VTs + chunk * 16ull / 2);
        }
        __syncthreads();

        f32x4 sf[4] = {};
#pragma unroll
        for (int kk = 0; kk < 2; ++kk)
#pragma unroll
            for (int nt = 0; nt < 4; ++nt) {
                bf16x8 bk = *(const bf16x8*)&Ks[(nt * 16 + l16) * 64 + kk * 32 + quad * 8];
                sf[nt] = MFMA16(aq[kk], bk, sf[nt]);
            }

        const bool diag = (kt == qi);
#pragma unroll
        for (int nt = 0; nt < 4; ++nt) {
            int col = kt * 64 + nt * 16 + l16;
#pragma unroll
            for (int r = 0; r < 4; ++r) {
                float s = sf[nt][r];
                if (diag && col > qrow + r) s = -1e30f;
                float p = __expf(s);
                lsum[r] += p;
                Ps[(wid * 16 + quad * 4 + r) * 64 + nt * 16 + l16] = (bf16_t)p;
            }
        }
#pragma unroll
        for (int kk = 0; kk < 2; ++kk) {
            bf16x8 ap = *(const bf16x8*)&Ps[(wid * 16 + l16) * 64 + kk * 32 + quad * 8];
#pragma unroll
            for (int dt = 0; dt < 4; ++dt) {
                bf16x8 bv = *(const bf16x8*)&VTs[(dt * 16 + l16) * 64 + kk * 32 + quad * 8];
                o[dt] = MFMA16(ap, bv, o[dt]);
            }
        }
    }

#pragma unroll
    for (int r = 0; r < 4; ++r) {
        float s = lsum[r];
#pragma unroll
        for (int off = 1; off < 16; off <<= 1) s += __shfl_xor(s, off, 16);
        float inv = 1.f / s;
        size_t row = (size_t)b * kT + qi * 64 + wid * 16 + quad * 4 + r;
#pragma unroll
        for (int dt = 0; dt < 4; ++dt)
            sa[row * kC + h * kD + dt * 16 + l16] = (bf16_t)(o[dt][r] * inv);
    }
}

// ---------------- fused cross-attn: scores + softmax(no-max) + PV ----------------
// q2: [b,t,c] bf16; k2: [b,s,c] bf16; v2T: [b,h,d,s] bf16
// ca out: [b,t,c] bf16; probs out: [b,h,t,s] fp32
__global__ __launch_bounds__(256) void ca_fused(const bf16_t* __restrict__ q2, const bf16_t* __restrict__ k2,
                                                const bf16_t* __restrict__ v2T, bf16_t* __restrict__ ca,
                                                float* __restrict__ probs) {
    const int tid = threadIdx.x;
    const int qi = blockIdx.x, z = blockIdx.y;
    const int b = z >> 4, h = z & 15;
    const int lane = tid & 63, wid = tid >> 6;
    const int l16 = lane & 15, quad = lane >> 4;
    const size_t bh = (size_t)z;

    __shared__ __align__(16) bf16_t Qs[64 * 64];
    __shared__ __align__(16) bf16_t Ks[64 * 64];
    __shared__ __align__(16) bf16_t VTs[64 * 64];
    bf16_t* Ps = Qs;

#pragma unroll
    for (int i = 0; i < 2; ++i) {
        int chunk = tid + i * 256;
        int row = chunk >> 3, col = (chunk & 7) * 8;
        gld_lds16(q2 + ((size_t)(b * kT + qi * 64 + row)) * kC + h * kD + col, Qs + chunk * 8);
    }
    __syncthreads();
    bf16x8 aq[2];
    aq[0] = *(const bf16x8*)&Qs[(wid * 16 + l16) * 64 + quad * 8];
    aq[1] = *(const bf16x8*)&Qs[(wid * 16 + l16) * 64 + 32 + quad * 8];
#pragma unroll
    for (int j = 0; j < 8; ++j) { aq[0][j] *= (bf16_t)0.125f; aq[1][j] *= (bf16_t)0.125f; }

    f32x4 o[4] = {};
    float lsum[4] = {0.f, 0.f, 0.f, 0.f};
    bf16x4 pk[9][4]; // packed P for final probs write (72 VGPRs)

#pragma unroll
    for (int kt = 0; kt < 9; ++kt) {
        __syncthreads();
#pragma unroll
        for (int i = 0; i < 2; ++i) {
            int chunk = tid + i * 256;
            int row = chunk >> 3, col = (chunk & 7) * 8;
            gld_lds16(k2 + ((size_t)(b * kS + kt * 64 + row)) * kC + h * kD + col, Ks + chunk * 8);
            gld_lds16(v2T + (bh * kD + row) * kS + kt * 64 + col, VTs + chunk * 8);
        }
        __syncthreads();

        f32x4 sf[4] = {};
#pragma unroll
        for (int kk = 0; kk < 2; ++kk)
#pragma unroll
            for (int nt = 0; nt < 4; ++nt) {
                bf16x8 bk = *(const bf16x8*)&Ks[(nt * 16 + l16) * 64 + kk * 32 + quad * 8];
                sf[nt] = MFMA16(aq[kk], bk, sf[nt]);
            }
#pragma unroll
        for (int nt = 0; nt < 4; ++nt) {
            bf16x4 pc;
#pragma unroll
            for (int r = 0; r < 4; ++r) {
                float p = __expf(sf[nt][r]);
                lsum[r] += p;
                bf16_t pb = (bf16_t)p;
                pc[r] = pb;
                Ps[(wid * 16 + quad * 4 + r) * 64 + nt * 16 + l16] = pb;
            }
            pk[kt][nt] = pc;
        }
#pragma unroll
        for (int kk = 0; kk < 2; ++kk) {
            bf16x8 ap = *(const bf16x8*)&Ps[(wid * 16 + l16) * 64 + kk * 32 + quad * 8];
#pragma unroll
            for (int dt = 0; dt < 4; ++dt) {
                bf16x8 bv = *(const bf16x8*)&VTs[(dt * 16 + l16) * 64 + kk * 32 + quad * 8];
                o[dt] = MFMA16(ap, bv, o[dt]);
            }
        }
    }

    float inv[4];
#pragma unroll
    for (int r = 0; r < 4; ++r) {
        float s = lsum[r];
#pragma unroll
        for (int off = 1; off < 16; off <<= 1) s += __shfl_xor(s, off, 16);
        inv[r] = 1.f / s;
        size_t row = (size_t)b * kT + qi * 64 + wid * 16 + quad * 4 + r;
#pragma unroll
        for (int dt = 0; dt < 4; ++dt)
            ca[row * kC + h * kD + dt * 16 + l16] = (bf16_t)(o[dt][r] * inv[r]);
    }
    // probs = p * inv  (fp32, [b,h,t,s])
#pragma unroll
    for (int r = 0; r < 4; ++r) {
        float* dst = probs + ((size_t)z * kT + qi * 64 + wid * 16 + quad * 4 + r) * kS;
#pragma unroll
        for (int kt = 0; kt < 9; ++kt)
#pragma unroll
            for (int nt = 0; nt < 4; ++nt)
                dst[kt * 64 + nt * 16 + l16] = (float)pk[kt][nt][r] * inv[r];
    }
}

// ---------------- v2 [B,S,C] -> v2T [B,H,D,S] ----------------
__global__ void v_transpose(const bf16_t* __restrict__ v2, bf16_t* __restrict__ v2T) {
    int idx = blockIdx.x * 256 + threadIdx.x;
    int s = idx % kS;
    int t = idx / kS;
    int d = t % kD; t /= kD;
    int h = t % kH;
    int b = t / kH;
    v2T[idx] = v2[((size_t)(b * kS + s)) * kC + h * kD + d];
}

extern "C" void kernel_launch(void* const* d_in, const int* in_sizes, int n_in, void* d_out, int out_size,
                              void* d_ws, size_t ws_size, hipStream_t stream) {
    const float* x = (const float*)d_in[0];
    const float* context = (const float*)d_in[1];
    const float* ln1_w = (const float*)d_in[2];
    const float* ln1_b = (const float*)d_in[3];
    const float* ln2_w = (const float*)d_in[4];
    const float* ln2_b = (const float*)d_in[5];
    const float* ln3_w = (const float*)d_in[6];
    const float* ln3_b = (const float*)d_in[7];
    const float* attn_wqkv = (const float*)d_in[8];
    const float* attn_bqkv = (const float*)d_in[9];
    const float* attn_wproj = (const float*)d_in[10];
    const float* attn_bproj = (const float*)d_in[11];
    const float* ca_wq = (const float*)d_in[12];
    const float* ca_bq = (const float*)d_in[13];
    const float* ca_wk = (const float*)d_in[14];
    const float* ca_bk = (const float*)d_in[15];
    const float* ca_wv = (const float*)d_in[16];
    const float* ca_bv = (const float*)d_in[17];
    const float* ca_wproj = (const float*)d_in[18];
    const float* ca_bproj = (const float*)d_in[19];
    const float* fc_w = (const float*)d_in[20];
    const float* fc_b = (const float*)d_in[21];
    const float* proj_w = (const float*)d_in[22];
    const float* proj_b = (const float*)d_in[23];

    float* out_x = (float*)d_out;
    float* probs = out_x + (size_t)kB * kT * kC;

    char* wsp = (char*)d_ws;
    size_t off = 0;
    auto alloc = [&](size_t bytes) -> void* {
        void* p = wsp + off;
        off += (bytes + 255) & ~(size_t)255;
        return p;
    };
    bf16_t* wT_qkv   = (bf16_t*)alloc((size_t)3 * kC * kC * 2);
    bf16_t* wT_aproj = (bf16_t*)alloc((size_t)kC * kC * 2);
    bf16_t* wT_caq   = (bf16_t*)alloc((size_t)kC * kC * 2);
    bf16_t* wT_cak   = (bf16_t*)alloc((size_t)kC * kC * 2);
    bf16_t* wT_cav   = (bf16_t*)alloc((size_t)kC * kC * 2);
    bf16_t* wT_caproj= (bf16_t*)alloc((size_t)kC * kC * 2);
    bf16_t* wT_fc    = (bf16_t*)alloc((size_t)4 * kC * kC * 2);
    bf16_t* wT_proj  = (bf16_t*)alloc((size_t)4 * kC * kC * 2);
    bf16_t* hbuf     = (bf16_t*)alloc((size_t)kB * kT * kC * 2);
    bf16_t* qb       = (bf16_t*)alloc((size_t)kB * kT * kC * 2);
    bf16_t* kbuf     = (bf16_t*)alloc((size_t)kB * kT * kC * 2);
    bf16_t* vTb      = (bf16_t*)alloc((size_t)kB * kT * kC * 2);
    bf16_t* sabuf    = (bf16_t*)alloc((size_t)kB * kT * kC * 2);
    float*  x1       = (float*)alloc((size_t)kB * kT * kC * 4);
    float*  x2       = (float*)alloc((size_t)kB * kT * kC * 4);
    bf16_t* ctxb     = (bf16_t*)alloc((size_t)kB * kS * kC * 2);
    bf16_t* q2       = (bf16_t*)alloc((size_t)kB * kT * kC * 2);
    bf16_t* k2       = (bf16_t*)alloc((size_t)kB * kS * kC * 2);
    bf16_t* v2       = (bf16_t*)alloc((size_t)kB * kS * kC * 2);
    bf16_t* v2T      = (bf16_t*)alloc((size_t)kB * kS * kC * 2);
    bf16_t* hf       = (bf16_t*)alloc((size_t)kB * kT * 4 * kC * 2);
    (void)ws_size;

    dim3 tb(32, 8);
    transpose_w<<<dim3(96, 32), tb, 0, stream>>>(attn_wqkv, wT_qkv, kC, 3 * kC);
    transpose_w<<<dim3(32, 32), tb, 0, stream>>>(attn_wproj, wT_aproj, kC, kC);
    transpose_w<<<dim3(32, 32), tb, 0, stream>>>(ca_wq, wT_caq, kC, kC);
    transpose_w<<<dim3(32, 32), tb, 0, stream>>>(ca_wk, wT_cak, kC, kC);
    transpose_w<<<dim3(32, 32), tb, 0, stream>>>(ca_wv, wT_cav, kC, kC);
    transpose_w<<<dim3(32, 32), tb, 0, stream>>>(ca_wproj, wT_caproj, kC, kC);
    transpose_w<<<dim3(128, 32), tb, 0, stream>>>(fc_w, wT_fc, kC, 4 * kC);
    transpose_w<<<dim3(32, 128), tb, 0, stream>>>(proj_w, wT_proj, 4 * kC, kC);
    f32_to_bf16<<<dim3((kB * kS * kC / 4 + 255) / 256), 256, 0, stream>>>(context, ctxb, kB * kS * kC / 4);

    const int Mtok = kB * kT;   // 4096
    const int n4tok = Mtok * kC / 4;
    // LN1 -> hbuf
    ln_kernel<<<Mtok, 256, 0, stream>>>(x, ln1_w, ln1_b, hbuf);
    // qkv split -> qb [b,h,t,d], kbuf [b,h,t,d], vTb [b,h,d,t]
    gemm128<4, 128><<<dim3(24, 32), 256, 0, stream>>>(hbuf, wT_qkv, attn_bqkv, nullptr, qb, kbuf, vTb, Mtok,
                                                      3 * kC, kC, kC, kC, 0);
    // flash self-attn (no-max)
    flash_self3<<<dim3(kT / 64, kH, kB), 256, 0, stream>>>(qb, kbuf, vTb, sabuf);
    // x1 = x + sa @ Wproj + b     (split-K=2, atomic accumulate into x1=x)
    copy_f32<<<dim3(n4tok / 256), 256, 0, stream>>>(x, x1, n4tok);
    gemm_sk<64><<<dim3(8, 64, 2), 256, 0, stream>>>(sabuf, wT_aproj, attn_bproj, x1, 512, kC, kC, kC);
    // LN2 -> hbuf
    ln_kernel<<<Mtok, 256, 0, stream>>>(x1, ln2_w, ln2_b, hbuf);
    // q2 = h @ Wq + b
    gemm128<0, 64><<<dim3(8, 64), 256, 0, stream>>>(hbuf, wT_caq, ca_bq, nullptr, q2, nullptr, nullptr, Mtok, kC,
                                                    kC, kC, kC, kC);
    // k2 / v2 from context
    gemm128<0, 64><<<dim3(8, 18), 256, 0, stream>>>(ctxb, wT_cak, ca_bk, nullptr, k2, nullptr, nullptr, kB * kS,
                                                    kC, kC, kC, kC, kC);
    gemm128<0, 64><<<dim3(8, 18), 256, 0, stream>>>(ctxb, wT_cav, ca_bv, nullptr, v2, nullptr, nullptr, kB * kS,
                                                    kC, kC, kC, kC, kC);
    v_transpose<<<dim3(kB * kH * kD * kS / 256), 256, 0, stream>>>(v2, v2T);
    // fused cross-attn: scores + softmax + PV -> sabuf (ca), probs (d_out)
    ca_fused<<<dim3(kT / 64, kB * kH), 256, 0, stream>>>(q2, k2, v2T, sabuf, probs);
    // x2 = x1 + ca @ Wcaproj + b  (split-K=2, atomic accumulate into x2=x1)
    copy_f32<<<dim3(n4tok / 256), 256, 0, stream>>>(x1, x2, n4tok);
    gemm_sk<64><<<dim3(8, 64, 2), 256, 0, stream>>>(sabuf, wT_caproj, ca_bproj, x2, 512, kC, kC, kC);
    // LN3 -> hbuf
    ln_kernel<<<Mtok, 256, 0, stream>>>(x2, ln3_w, ln3_b, hbuf);
    // hf = gelu(h @ fc_w + b)
    gemm128<2, 128><<<dim3(32, 32), 256, 0, stream>>>(hbuf, wT_fc, fc_b, nullptr, hf, nullptr, nullptr, Mtok,
                                                      4 * kC, kC, kC, kC, 4 * kC);
    // out = x2 + hf @ proj_w + b  (split-K=4, BM=128, atomic accumulate into out=x2)
    copy_f32<<<dim3(n4tok / 256), 256, 0, stream>>>(x2, out_x, n4tok);
    gemm_sk<128><<<dim3(8, 32, 4), 256, 0, stream>>>(hf, wT_proj, proj_b, out_x, 1024, 4 * kC, 4 * kC, kC);
}

// Round 2
// 773.612 us; speedup vs baseline: 1.0646x; 1.0646x over previous
//
#include <hip/hip_runtime.h>

typedef __bf16 bf16_t;
typedef __attribute__((ext_vector_type(8))) __bf16 bf16x8;
typedef __attribute__((ext_vector_type(4))) __bf16 bf16x4;
typedef __attribute__((ext_vector_type(4))) float f32x4;

static constexpr int kB = 2, kT = 2048, kS = 576, kC = 1024, kH = 16, kD = 64;

#define MFMA16(a, b, c) __builtin_amdgcn_mfma_f32_16x16x32_bf16((a), (b), (c), 0, 0, 0)

__device__ __forceinline__ void gld_lds16(const bf16_t* g, bf16_t* l) {
    __builtin_amdgcn_global_load_lds((const __attribute__((address_space(1))) unsigned int*)g,
                                     (__attribute__((address_space(3))) unsigned int*)l, 16, 0, 0);
}

__device__ inline float gelu_tanh(float x) {
    float u = 1.5957691216057308f * (x + 0.044715f * x * x * x);
    float t = 1.f - 2.f / (__expf(u) + 1.f);
    return 0.5f * x * (1.f + t);
}

// ---------------- weight transpose + f32->bf16: W[K,N] -> WT[N,K] ----------------
__global__ void transpose_w(const float* __restrict__ W, bf16_t* __restrict__ WT, int K, int N) {
    __shared__ float tile[32][33];
    int n0 = blockIdx.x * 32, k0 = blockIdx.y * 32;
    int tx = threadIdx.x, ty = threadIdx.y;
#pragma unroll
    for (int i = 0; i < 4; ++i)
        tile[ty + i * 8][tx] = W[(size_t)(k0 + ty + i * 8) * N + n0 + tx];
    __syncthreads();
#pragma unroll
    for (int i = 0; i < 4; ++i)
        WT[(size_t)(n0 + ty + i * 8) * K + k0 + tx] = (bf16_t)tile[tx][ty + i * 8];
}

// ---------------- f32 -> bf16 elementwise (n4 = count/4) ----------------
__global__ void f32_to_bf16(const float* __restrict__ in, bf16_t* __restrict__ out, int n4) {
    int i = blockIdx.x * 256 + threadIdx.x;
    if (i < n4) {
        float4 v = ((const float4*)in)[i];
        bf16x4 o;
        o[0] = (bf16_t)v.x; o[1] = (bf16_t)v.y; o[2] = (bf16_t)v.z; o[3] = (bf16_t)v.w;
        ((bf16x4*)out)[i] = o;
    }
}

// ---------------- LayerNorm: fp32 in [rows, 1024] -> bf16 out ----------------
__global__ __launch_bounds__(256) void ln_kernel(const float* __restrict__ x,
                                                 const float* __restrict__ w,
                                                 const float* __restrict__ bb,
                                                 bf16_t* __restrict__ out) {
    int row = blockIdx.x, tid = threadIdx.x;
    const float* xr = x + (size_t)row * kC;
    float4 v = ((const float4*)xr)[tid];
    float s1 = v.x + v.y + v.z + v.w;
    float s2 = v.x * v.x + v.y * v.y + v.z * v.z + v.w * v.w;
#pragma unroll
    for (int o = 32; o > 0; o >>= 1) {
        s1 += __shfl_down(s1, o);
        s2 += __shfl_down(s2, o);
    }
    __shared__ float red[8];
    __shared__ float mv[2];
    int wid = tid >> 6, lane = tid & 63;
    if (lane == 0) { red[wid] = s1; red[4 + wid] = s2; }
    __syncthreads();
    if (tid == 0) {
        float a = red[0] + red[1] + red[2] + red[3];
        float c = red[4] + red[5] + red[6] + red[7];
        float mean = a * (1.f / kC);
        float var = c * (1.f / kC) - mean * mean;
        mv[0] = mean;
        mv[1] = rsqrtf(var + 1e-5f);
    }
    __syncthreads();
    float mean = mv[0], rstd = mv[1];
    float4 wv = ((const float4*)w)[tid];
    float4 bv = ((const float4*)bb)[tid];
    bf16x4 o4;
    o4[0] = (bf16_t)((v.x - mean) * rstd * wv.x + bv.x);
    o4[1] = (bf16_t)((v.y - mean) * rstd * wv.y + bv.y);
    o4[2] = (bf16_t)((v.z - mean) * rstd * wv.z + bv.z);
    o4[3] = (bf16_t)((v.w - mean) * rstd * wv.w + bv.w);
    *(bf16x4*)&out[(size_t)row * kC + tid * 4] = o4;
}

// ---------------- 2-phase double-buffered GEMM: C[M,N] = A[M,K] @ WT[N,K]^T (+epilogue) ----------------
// EPI: 0 bf16+bias, 1 f32 = acc+bias+res, 2 bf16 gelu(acc+bias), 4 qkv-split (Out=q,Out2=k,Out3=vT)
template <int EPI, int BM>
__global__ __launch_bounds__(256) void gemm128(const bf16_t* __restrict__ A, const bf16_t* __restrict__ Bw,
                                               const float* __restrict__ bias, const float* __restrict__ res,
                                               void* __restrict__ Out, void* __restrict__ Out2,
                                               void* __restrict__ Out3, int M, int N, int K, int lda, int ldb,
                                               int ldc) {
    constexpr int MT = BM / 32;
    constexpr int ASZ = BM * 64, BSZ = 128 * 64;
    __shared__ __align__(16) bf16_t As[2 * ASZ];
    __shared__ __align__(16) bf16_t Bs[2 * BSZ];
    const int tid = threadIdx.x;
    const int m0 = blockIdx.y * BM, n0 = blockIdx.x * 128;
    const int lane = tid & 63, wid = tid >> 6;
    const int l16 = lane & 15, quad = lane >> 4;
    const int wm = (wid >> 1) * (BM / 2), wn = (wid & 1) * 64;
    f32x4 acc[MT][4] = {};

    const bf16_t* Ab = A + (size_t)m0 * lda;
    const bf16_t* Bb = Bw + (size_t)n0 * ldb;

    auto stage = [&](int buf, int k0) {
#pragma unroll
        for (int i = 0; i < BM / 32; ++i) {
            int chunk = tid + i * 256;
            int row = chunk >> 3, col = (chunk & 7) * 8;
            gld_lds16(Ab + (size_t)row * lda + k0 + col, As + buf * ASZ + row * 64 + col);
        }
#pragma unroll
        for (int i = 0; i < 4; ++i) {
            int chunk = tid + i * 256;
            int row = chunk >> 3, col = (chunk & 7) * 8;
            gld_lds16(Bb + (size_t)row * ldb + k0 + col, Bs + buf * BSZ + row * 64 + col);
        }
    };

    const int nk = K / 64;
    stage(0, 0);
    int cur = 0;
    for (int t = 0; t < nk; ++t) {
        __syncthreads();  // drains staged loads for buf `cur`; guards overwrite of the other buf
        if (t + 1 < nk) stage(cur ^ 1, (t + 1) * 64);
#pragma unroll
        for (int kk = 0; kk < 64; kk += 32) {
            bf16x8 af[MT], bw[4];
#pragma unroll
            for (int mt = 0; mt < MT; ++mt)
                af[mt] = *(const bf16x8*)&As[cur * ASZ + (wm + mt * 16 + l16) * 64 + kk + quad * 8];
#pragma unroll
            for (int nt = 0; nt < 4; ++nt)
                bw[nt] = *(const bf16x8*)&Bs[cur * BSZ + (wn + nt * 16 + l16) * 64 + kk + quad * 8];
#pragma unroll
            for (int mt = 0; mt < MT; ++mt)
#pragma unroll
                for (int nt = 0; nt < 4; ++nt) acc[mt][nt] = MFMA16(af[mt], bw[nt], acc[mt][nt]);
        }
        cur ^= 1;
    }

#pragma unroll
    for (int mt = 0; mt < MT; ++mt)
#pragma unroll
        for (int nt = 0; nt < 4; ++nt) {
            int n = n0 + wn + nt * 16 + l16;
            float bv = bias ? bias[n] : 0.f;
#pragma unroll
            for (int r = 0; r < 4; ++r) {
                int m = m0 + wm + mt * 16 + quad * 4 + r;
                float v = acc[mt][nt][r] + bv;
                if constexpr (EPI == 2) v = gelu_tanh(v);
                if constexpr (EPI == 0 || EPI == 2) {
                    ((bf16_t*)Out)[(size_t)m * ldc + n] = (bf16_t)v;
                } else if constexpr (EPI == 1) {
                    ((float*)Out)[(size_t)m * ldc + n] = v + res[(size_t)m * ldc + n];
                } else { // EPI 4: qkv split
                    int b = m >> 11, t = m & 2047;
                    if (n < 2048) {
                        int h = (n & 1023) >> 6, d = n & 63;
                        bf16_t* dst = (n < 1024) ? (bf16_t*)Out : (bf16_t*)Out2;
                        dst[(((size_t)b * kH + h) * kT + t) * kD + d] = (bf16_t)v;
                    } else {
                        int n2 = n - 2048;
                        int h = n2 >> 6, d = n2 & 63;
                        ((bf16_t*)Out3)[(((size_t)b * kH + h) * kD + d) * kT + t] = (bf16_t)v;
                    }
                }
            }
        }
}

// ---------------- flash causal self-attention v3 (no-max softmax) ----------------
// q,k: [b,h,t,d] bf16; vT: [b,h,d,t] bf16; sa out: [b,t,c] bf16
__global__ __launch_bounds__(256) void flash_self3(const bf16_t* __restrict__ qb, const bf16_t* __restrict__ kb,
                                                   const bf16_t* __restrict__ vT, bf16_t* __restrict__ sa) {
    const int tid = threadIdx.x;
    const int qi = gridDim.x - 1 - blockIdx.x; // heavy blocks first
    const int h = blockIdx.y, b = blockIdx.z;
    const int lane = tid & 63, wid = tid >> 6;
    const int l16 = lane & 15, quad = lane >> 4;
    const size_t bh = (size_t)b * kH + h;

    __shared__ __align__(16) bf16_t Qs[64 * 64];
    __shared__ __align__(16) bf16_t Ks[64 * 64];
    __shared__ __align__(16) bf16_t VTs[64 * 64];
    bf16_t* Ps = Qs; // reuse after Q frags are hoisted

    const bf16_t* qsrc = qb + (bh * kT + (size_t)qi * 64) * kD;
#pragma unroll
    for (int i = 0; i < 2; ++i) {
        int chunk = tid + i * 256;
        gld_lds16(qsrc + chunk * 8, Qs + chunk * 8);
    }
    __syncthreads();
    bf16x8 aq[2];
    aq[0] = *(const bf16x8*)&Qs[(wid * 16 + l16) * 64 + quad * 8];
    aq[1] = *(const bf16x8*)&Qs[(wid * 16 + l16) * 64 + 32 + quad * 8];
#pragma unroll
    for (int j = 0; j < 8; ++j) { aq[0][j] *= (bf16_t)0.125f; aq[1][j] *= (bf16_t)0.125f; } // exact pow2

    f32x4 o[4] = {};
    float lsum[4] = {0.f, 0.f, 0.f, 0.f};
    const int qrow = qi * 64 + wid * 16 + quad * 4;

    for (int kt = 0; kt <= qi; ++kt) {
        __syncthreads();
        const bf16_t* ksrc = kb + (bh * kT + (size_t)kt * 64) * kD;
        const bf16_t* vsrc = vT + bh * kD * kT + (size_t)kt * 64;
#pragma unroll
        for (int i = 0; i < 2; ++i) {
            int chunk = tid + i * 256;
            gld_lds16(ksrc + chunk * 8, Ks + chunk * 8);
            int row = chunk >> 3, col = (chunk & 7) * 8;
            gld_lds16(vsrc + (size_t)row * kT + col, VTs + chunk * 16ull / 2);
        }
        __syncthreads();

        f32x4 sf[4] = {};
#pragma unroll
        for (int kk = 0; kk < 2; ++kk)
#pragma unroll
            for (int nt = 0; nt < 4; ++nt) {
                bf16x8 bk = *(const bf16x8*)&Ks[(nt * 16 + l16) * 64 + kk * 32 + quad * 8];
                sf[nt] = MFMA16(aq[kk], bk, sf[nt]);
            }

        const bool diag = (kt == qi);
#pragma unroll
        for (int nt = 0; nt < 4; ++nt) {
            int col = kt * 64 + nt * 16 + l16;
#pragma unroll
            for (int r = 0; r < 4; ++r) {
                float s = sf[nt][r];
                if (diag && col > qrow + r) s = -1e30f;
                float p = __expf(s);
                lsum[r] += p;
                Ps[(wid * 16 + quad * 4 + r) * 64 + nt * 16 + l16] = (bf16_t)p;
            }
        }
#pragma unroll
        for (int kk = 0; kk < 2; ++kk) {
            bf16x8 ap = *(const bf16x8*)&Ps[(wid * 16 + l16) * 64 + kk * 32 + quad * 8];
#pragma unroll
            for (int dt = 0; dt < 4; ++dt) {
                bf16x8 bv = *(const bf16x8*)&VTs[(dt * 16 + l16) * 64 + kk * 32 + quad * 8];
                o[dt] = MFMA16(ap, bv, o[dt]);
            }
        }
    }

#pragma unroll
    for (int r = 0; r < 4; ++r) {
        float s = lsum[r];
#pragma unroll
        for (int off = 1; off < 16; off <<= 1) s += __shfl_xor(s, off, 16);
        float inv = 1.f / s;
        size_t row = (size_t)b * kT + qi * 64 + wid * 16 + quad * 4 + r;
#pragma unroll
        for (int dt = 0; dt < 4; ++dt)
            sa[row * kC + h * kD + dt * 16 + l16] = (bf16_t)(o[dt][r] * inv);
    }
}

// ---------------- fused cross-attn: scores + softmax(no-max) + PV ----------------
// q2: [b,t,c] bf16; k2: [b,s,c] bf16; v2T: [b,h,d,s] bf16
// ca out: [b,t,c] bf16; probs out: [b,h,t,s] fp32
__global__ __launch_bounds__(256) void ca_fused(const bf16_t* __restrict__ q2, const bf16_t* __restrict__ k2,
                                                const bf16_t* __restrict__ v2T, bf16_t* __restrict__ ca,
                                                float* __restrict__ probs) {
    const int tid = threadIdx.x;
    const int qi = blockIdx.x, z = blockIdx.y;
    const int b = z >> 4, h = z & 15;
    const int lane = tid & 63, wid = tid >> 6;
    const int l16 = lane & 15, quad = lane >> 4;
    const size_t bh = (size_t)z;

    __shared__ __align__(16) bf16_t Qs[64 * 64];
    __shared__ __align__(16) bf16_t Ks[64 * 64];
    __shared__ __align__(16) bf16_t VTs[64 * 64];
    bf16_t* Ps = Qs;

#pragma unroll
    for (int i = 0; i < 2; ++i) {
        int chunk = tid + i * 256;
        int row = chunk >> 3, col = (chunk & 7) * 8;
        gld_lds16(q2 + ((size_t)(b * kT + qi * 64 + row)) * kC + h * kD + col, Qs + chunk * 8);
    }
    __syncthreads();
    bf16x8 aq[2];
    aq[0] = *(const bf16x8*)&Qs[(wid * 16 + l16) * 64 + quad * 8];
    aq[1] = *(const bf16x8*)&Qs[(wid * 16 + l16) * 64 + 32 + quad * 8];
#pragma unroll
    for (int j = 0; j < 8; ++j) { aq[0][j] *= (bf16_t)0.125f; aq[1][j] *= (bf16_t)0.125f; }

    f32x4 o[4] = {};
    float lsum[4] = {0.f, 0.f, 0.f, 0.f};
    bf16x4 pk[9][4]; // packed P for final probs write (72 VGPRs)

#pragma unroll
    for (int kt = 0; kt < 9; ++kt) {
        __syncthreads();
#pragma unroll
        for (int i = 0; i < 2; ++i) {
            int chunk = tid + i * 256;
            int row = chunk >> 3, col = (chunk & 7) * 8;
            gld_lds16(k2 + ((size_t)(b * kS + kt * 64 + row)) * kC + h * kD + col, Ks + chunk * 8);
            gld_lds16(v2T + (bh * kD + row) * kS + kt * 64 + col, VTs + chunk * 8);
        }
        __syncthreads();

        f32x4 sf[4] = {};
#pragma unroll
        for (int kk = 0; kk < 2; ++kk)
#pragma unroll
            for (int nt = 0; nt < 4; ++nt) {
                bf16x8 bk = *(const bf16x8*)&Ks[(nt * 16 + l16) * 64 + kk * 32 + quad * 8];
                sf[nt] = MFMA16(aq[kk], bk, sf[nt]);
            }
#pragma unroll
        for (int nt = 0; nt < 4; ++nt) {
            bf16x4 pc;
#pragma unroll
            for (int r = 0; r < 4; ++r) {
                float p = __expf(sf[nt][r]);
                lsum[r] += p;
                bf16_t pb = (bf16_t)p;
                pc[r] = pb;
                Ps[(wid * 16 + quad * 4 + r) * 64 + nt * 16 + l16] = pb;
            }
            pk[kt][nt] = pc;
        }
#pragma unroll
        for (int kk = 0; kk < 2; ++kk) {
            bf16x8 ap = *(const bf16x8*)&Ps[(wid * 16 + l16) * 64 + kk * 32 + quad * 8];
#pragma unroll
            for (int dt = 0; dt < 4; ++dt) {
                bf16x8 bv = *(const bf16x8*)&VTs[(dt * 16 + l16) * 64 + kk * 32 + quad * 8];
                o[dt] = MFMA16(ap, bv, o[dt]);
            }
        }
    }

    float inv[4];
#pragma unroll
    for (int r = 0; r < 4; ++r) {
        float s = lsum[r];
#pragma unroll
        for (int off = 1; off < 16; off <<= 1) s += __shfl_xor(s, off, 16);
        inv[r] = 1.f / s;
        size_t row = (size_t)b * kT + qi * 64 + wid * 16 + quad * 4 + r;
#pragma unroll
        for (int dt = 0; dt < 4; ++dt)
            ca[row * kC + h * kD + dt * 16 + l16] = (bf16_t)(o[dt][r] * inv[r]);
    }
    // probs = p * inv  (fp32, [b,h,t,s])
#pragma unroll
    for (int r = 0; r < 4; ++r) {
        float* dst = probs + ((size_t)z * kT + qi * 64 + wid * 16 + quad * 4 + r) * kS;
#pragma unroll
        for (int kt = 0; kt < 9; ++kt)
#pragma unroll
            for (int nt = 0; nt < 4; ++nt)
                dst[kt * 64 + nt * 16 + l16] = (float)pk[kt][nt][r] * inv[r];
    }
}

// ---------------- v2 [B,S,C] -> v2T [B,H,D,S] ----------------
__global__ void v_transpose(const bf16_t* __restrict__ v2, bf16_t* __restrict__ v2T) {
    int idx = blockIdx.x * 256 + threadIdx.x;
    int s = idx % kS;
    int t = idx / kS;
    int d = t % kD; t /= kD;
    int h = t % kH;
    int b = t / kH;
    v2T[idx] = v2[((size_t)(b * kS + s)) * kC + h * kD + d];
}

extern "C" void kernel_launch(void* const* d_in, const int* in_sizes, int n_in, void* d_out, int out_size,
                              void* d_ws, size_t ws_size, hipStream_t stream) {
    const float* x = (const float*)d_in[0];
    const float* context = (const float*)d_in[1];
    const float* ln1_w = (const float*)d_in[2];
    const float* ln1_b = (const float*)d_in[3];
    const float* ln2_w = (const float*)d_in[4];
    const float* ln2_b = (const float*)d_in[5];
    const float* ln3_w = (const float*)d_in[6];
    const float* ln3_b = (const float*)d_in[7];
    const float* attn_wqkv = (const float*)d_in[8];
    const float* attn_bqkv = (const float*)d_in[9];
    const float* attn_wproj = (const float*)d_in[10];
    const float* attn_bproj = (const float*)d_in[11];
    const float* ca_wq = (const float*)d_in[12];
    const float* ca_bq = (const float*)d_in[13];
    const float* ca_wk = (const float*)d_in[14];
    const float* ca_bk = (const float*)d_in[15];
    const float* ca_wv = (const float*)d_in[16];
    const float* ca_bv = (const float*)d_in[17];
    const float* ca_wproj = (const float*)d_in[18];
    const float* ca_bproj = (const float*)d_in[19];
    const float* fc_w = (const float*)d_in[20];
    const float* fc_b = (const float*)d_in[21];
    const float* proj_w = (const float*)d_in[22];
    const float* proj_b = (const float*)d_in[23];

    float* out_x = (float*)d_out;
    float* probs = out_x + (size_t)kB * kT * kC;

    char* wsp = (char*)d_ws;
    size_t off = 0;
    auto alloc = [&](size_t bytes) -> void* {
        void* p = wsp + off;
        off += (bytes + 255) & ~(size_t)255;
        return p;
    };
    bf16_t* wT_qkv   = (bf16_t*)alloc((size_t)3 * kC * kC * 2);
    bf16_t* wT_aproj = (bf16_t*)alloc((size_t)kC * kC * 2);
    bf16_t* wT_caq   = (bf16_t*)alloc((size_t)kC * kC * 2);
    bf16_t* wT_cak   = (bf16_t*)alloc((size_t)kC * kC * 2);
    bf16_t* wT_cav   = (bf16_t*)alloc((size_t)kC * kC * 2);
    bf16_t* wT_caproj= (bf16_t*)alloc((size_t)kC * kC * 2);
    bf16_t* wT_fc    = (bf16_t*)alloc((size_t)4 * kC * kC * 2);
    bf16_t* wT_proj  = (bf16_t*)alloc((size_t)4 * kC * kC * 2);
    bf16_t* hbuf     = (bf16_t*)alloc((size_t)kB * kT * kC * 2);
    bf16_t* qb       = (bf16_t*)alloc((size_t)kB * kT * kC * 2);
    bf16_t* kbuf     = (bf16_t*)alloc((size_t)kB * kT * kC * 2);
    bf16_t* vTb      = (bf16_t*)alloc((size_t)kB * kT * kC * 2);
    bf16_t* sabuf    = (bf16_t*)alloc((size_t)kB * kT * kC * 2);
    float*  x1       = (float*)alloc((size_t)kB * kT * kC * 4);
    float*  x2       = (float*)alloc((size_t)kB * kT * kC * 4);
    bf16_t* ctxb     = (bf16_t*)alloc((size_t)kB * kS * kC * 2);
    bf16_t* q2       = (bf16_t*)alloc((size_t)kB * kT * kC * 2);
    bf16_t* k2       = (bf16_t*)alloc((size_t)kB * kS * kC * 2);
    bf16_t* v2       = (bf16_t*)alloc((size_t)kB * kS * kC * 2);
    bf16_t* v2T      = (bf16_t*)alloc((size_t)kB * kS * kC * 2);
    bf16_t* hf       = (bf16_t*)alloc((size_t)kB * kT * 4 * kC * 2);
    (void)ws_size;

    dim3 tb(32, 8);
    transpose_w<<<dim3(96, 32), tb, 0, stream>>>(attn_wqkv, wT_qkv, kC, 3 * kC);
    transpose_w<<<dim3(32, 32), tb, 0, stream>>>(attn_wproj, wT_aproj, kC, kC);
    transpose_w<<<dim3(32, 32), tb, 0, stream>>>(ca_wq, wT_caq, kC, kC);
    transpose_w<<<dim3(32, 32), tb, 0, stream>>>(ca_wk, wT_cak, kC, kC);
    transpose_w<<<dim3(32, 32), tb, 0, stream>>>(ca_wv, wT_cav, kC, kC);
    transpose_w<<<dim3(32, 32), tb, 0, stream>>>(ca_wproj, wT_caproj, kC, kC);
    transpose_w<<<dim3(128, 32), tb, 0, stream>>>(fc_w, wT_fc, kC, 4 * kC);
    transpose_w<<<dim3(32, 128), tb, 0, stream>>>(proj_w, wT_proj, 4 * kC, kC);
    f32_to_bf16<<<dim3((kB * kS * kC / 4 + 255) / 256), 256, 0, stream>>>(context, ctxb, kB * kS * kC / 4);

    const int Mtok = kB * kT;   // 4096
    // LN1 -> hbuf
    ln_kernel<<<Mtok, 256, 0, stream>>>(x, ln1_w, ln1_b, hbuf);
    // qkv split -> qb [b,h,t,d], kbuf [b,h,t,d], vTb [b,h,d,t]
    gemm128<4, 128><<<dim3(24, 32), 256, 0, stream>>>(hbuf, wT_qkv, attn_bqkv, nullptr, qb, kbuf, vTb, Mtok,
                                                      3 * kC, kC, kC, kC, 0);
    // flash self-attn (no-max)
    flash_self3<<<dim3(kT / 64, kH, kB), 256, 0, stream>>>(qb, kbuf, vTb, sabuf);
    // x1 = x + sa @ Wproj + b
    gemm128<1, 64><<<dim3(8, 64), 256, 0, stream>>>(sabuf, wT_aproj, attn_bproj, x, x1, nullptr, nullptr, Mtok,
                                                    kC, kC, kC, kC, kC);
    // LN2 -> hbuf
    ln_kernel<<<Mtok, 256, 0, stream>>>(x1, ln2_w, ln2_b, hbuf);
    // q2 = h @ Wq + b
    gemm128<0, 64><<<dim3(8, 64), 256, 0, stream>>>(hbuf, wT_caq, ca_bq, nullptr, q2, nullptr, nullptr, Mtok, kC,
                                                    kC, kC, kC, kC);
    // k2 / v2 from context
    gemm128<0, 64><<<dim3(8, 18), 256, 0, stream>>>(ctxb, wT_cak, ca_bk, nullptr, k2, nullptr, nullptr, kB * kS,
                                                    kC, kC, kC, kC, kC);
    gemm128<0, 64><<<dim3(8, 18), 256, 0, stream>>>(ctxb, wT_cav, ca_bv, nullptr, v2, nullptr, nullptr, kB * kS,
                                                    kC, kC, kC, kC, kC);
    v_transpose<<<dim3(kB * kH * kD * kS / 256), 256, 0, stream>>>(v2, v2T);
    // fused cross-attn: scores + softmax + PV -> sabuf (ca), probs (d_out)
    ca_fused<<<dim3(kT / 64, kB * kH), 256, 0, stream>>>(q2, k2, v2T, sabuf, probs);
    // x2 = x1 + ca @ Wcaproj + b
    gemm128<1, 64><<<dim3(8, 64), 256, 0, stream>>>(sabuf, wT_caproj, ca_bproj, x1, x2, nullptr, nullptr, Mtok,
                                                    kC, kC, kC, kC, kC);
    // LN3 -> hbuf
    ln_kernel<<<Mtok, 256, 0, stream>>>(x2, ln3_w, ln3_b, hbuf);
    // hf = gelu(h @ fc_w + b)
    gemm128<2, 128><<<dim3(32, 32), 256, 0, stream>>>(hbuf, wT_fc, fc_b, nullptr, hf, nullptr, nullptr, Mtok,
                                                      4 * kC, kC, kC, kC, 4 * kC);
    // out = x2 + hf @ proj_w + b
    gemm128<1, 64><<<dim3(8, 64), 256, 0, stream>>>(hf, wT_proj, proj_b, x2, out_x, nullptr, nullptr, Mtok, kC,
                                                    4 * kC, 4 * kC, 4 * kC, kC);
}

// Round 3
// 762.512 us; speedup vs baseline: 1.0801x; 1.0146x over previous
//
#include <hip/hip_runtime.h>

typedef __bf16 bf16_t;
typedef __attribute__((ext_vector_type(8))) __bf16 bf16x8;
typedef __attribute__((ext_vector_type(4))) __bf16 bf16x4;
typedef __attribute__((ext_vector_type(4))) float f32x4;

static constexpr int kB = 2, kT = 2048, kS = 576, kC = 1024, kH = 16, kD = 64;

#define MFMA16(a, b, c) __builtin_amdgcn_mfma_f32_16x16x32_bf16((a), (b), (c), 0, 0, 0)

__device__ __forceinline__ void gld_lds16(const bf16_t* g, bf16_t* l) {
    __builtin_amdgcn_global_load_lds((const __attribute__((address_space(1))) unsigned int*)g,
                                     (__attribute__((address_space(3))) unsigned int*)l, 16, 0, 0);
}

// swizzled read offset (elements) for a [64-col] bf16 LDS tile staged with
// pre-swizzled global source: logical 16B-unit column q of `row` lives at q^(row&7).
__device__ __forceinline__ int swz(int row, int q) { return row * 64 + (((q ^ (row & 7)) & 7) << 3); }

__device__ inline float gelu_tanh(float x) {
    float u = 1.5957691216057308f * (x + 0.044715f * x * x * x);
    float t = 1.f - 2.f / (__expf(u) + 1.f);
    return 0.5f * x * (1.f + t);
}

// ---------------- weight transpose + f32->bf16: W[K,N] -> WT[N,K] ----------------
__global__ void transpose_w(const float* __restrict__ W, bf16_t* __restrict__ WT, int K, int N) {
    __shared__ float tile[32][33];
    int n0 = blockIdx.x * 32, k0 = blockIdx.y * 32;
    int tx = threadIdx.x, ty = threadIdx.y;
#pragma unroll
    for (int i = 0; i < 4; ++i)
        tile[ty + i * 8][tx] = W[(size_t)(k0 + ty + i * 8) * N + n0 + tx];
    __syncthreads();
#pragma unroll
    for (int i = 0; i < 4; ++i)
        WT[(size_t)(n0 + ty + i * 8) * K + k0 + tx] = (bf16_t)tile[tx][ty + i * 8];
}

// ---------------- f32 -> bf16 elementwise (n4 = count/4) ----------------
__global__ void f32_to_bf16(const float* __restrict__ in, bf16_t* __restrict__ out, int n4) {
    int i = blockIdx.x * 256 + threadIdx.x;
    if (i < n4) {
        float4 v = ((const float4*)in)[i];
        bf16x4 o;
        o[0] = (bf16_t)v.x; o[1] = (bf16_t)v.y; o[2] = (bf16_t)v.z; o[3] = (bf16_t)v.w;
        ((bf16x4*)out)[i] = o;
    }
}

// ---------------- LayerNorm: fp32 in [rows, 1024] -> bf16 out ----------------
__global__ __launch_bounds__(256) void ln_kernel(const float* __restrict__ x,
                                                 const float* __restrict__ w,
                                                 const float* __restrict__ bb,
                                                 bf16_t* __restrict__ out) {
    int row = blockIdx.x, tid = threadIdx.x;
    const float* xr = x + (size_t)row * kC;
    float4 v = ((const float4*)xr)[tid];
    float s1 = v.x + v.y + v.z + v.w;
    float s2 = v.x * v.x + v.y * v.y + v.z * v.z + v.w * v.w;
#pragma unroll
    for (int o = 32; o > 0; o >>= 1) {
        s1 += __shfl_down(s1, o);
        s2 += __shfl_down(s2, o);
    }
    __shared__ float red[8];
    __shared__ float mv[2];
    int wid = tid >> 6, lane = tid & 63;
    if (lane == 0) { red[wid] = s1; red[4 + wid] = s2; }
    __syncthreads();
    if (tid == 0) {
        float a = red[0] + red[1] + red[2] + red[3];
        float c = red[4] + red[5] + red[6] + red[7];
        float mean = a * (1.f / kC);
        float var = c * (1.f / kC) - mean * mean;
        mv[0] = mean;
        mv[1] = rsqrtf(var + 1e-5f);
    }
    __syncthreads();
    float mean = mv[0], rstd = mv[1];
    float4 wv = ((const float4*)w)[tid];
    float4 bv = ((const float4*)bb)[tid];
    bf16x4 o4;
    o4[0] = (bf16_t)((v.x - mean) * rstd * wv.x + bv.x);
    o4[1] = (bf16_t)((v.y - mean) * rstd * wv.y + bv.y);
    o4[2] = (bf16_t)((v.z - mean) * rstd * wv.z + bv.z);
    o4[3] = (bf16_t)((v.w - mean) * rstd * wv.w + bv.w);
    *(bf16x4*)&out[(size_t)row * kC + tid * 4] = o4;
}

// ---------------- 2-phase double-buffered GEMM: C[M,N] = A[M,K] @ WT[N,K]^T (+epilogue) ----------------
// EPI: 0 bf16+bias, 1 f32 = acc+bias+res, 2 bf16 gelu(acc+bias), 4 qkv-split (Out=q,Out2=k,Out3=vT)
template <int EPI, int BM>
__global__ __launch_bounds__(256) void gemm128(const bf16_t* __restrict__ A, const bf16_t* __restrict__ Bw,
                                               const float* __restrict__ bias, const float* __restrict__ res,
                                               void* __restrict__ Out, void* __restrict__ Out2,
                                               void* __restrict__ Out3, int M, int N, int K, int lda, int ldb,
                                               int ldc) {
    constexpr int MT = BM / 32;
    constexpr int ASZ = BM * 64, BSZ = 128 * 64;
    __shared__ __align__(16) bf16_t As[2 * ASZ];
    __shared__ __align__(16) bf16_t Bs[2 * BSZ];
    const int tid = threadIdx.x;
    const int m0 = blockIdx.y * BM, n0 = blockIdx.x * 128;
    const int lane = tid & 63, wid = tid >> 6;
    const int l16 = lane & 15, quad = lane >> 4;
    const int wm = (wid >> 1) * (BM / 2), wn = (wid & 1) * 64;
    f32x4 acc[MT][4] = {};

    const bf16_t* Ab = A + (size_t)m0 * lda;
    const bf16_t* Bb = Bw + (size_t)n0 * ldb;

    auto stage = [&](int buf, int k0) {
#pragma unroll
        for (int i = 0; i < BM / 32; ++i) {
            int chunk = tid + i * 256;
            int row = chunk >> 3, col = (chunk & 7) * 8;
            gld_lds16(Ab + (size_t)row * lda + k0 + col, As + buf * ASZ + row * 64 + col);
        }
#pragma unroll
        for (int i = 0; i < 4; ++i) {
            int chunk = tid + i * 256;
            int row = chunk >> 3, col = (chunk & 7) * 8;
            gld_lds16(Bb + (size_t)row * ldb + k0 + col, Bs + buf * BSZ + row * 64 + col);
        }
    };

    const int nk = K / 64;
    stage(0, 0);
    int cur = 0;
    for (int t = 0; t < nk; ++t) {
        __syncthreads();  // drains staged loads for buf `cur`; guards overwrite of the other buf
        if (t + 1 < nk) stage(cur ^ 1, (t + 1) * 64);
#pragma unroll
        for (int kk = 0; kk < 64; kk += 32) {
            bf16x8 af[MT], bw[4];
#pragma unroll
            for (int mt = 0; mt < MT; ++mt)
                af[mt] = *(const bf16x8*)&As[cur * ASZ + (wm + mt * 16 + l16) * 64 + kk + quad * 8];
#pragma unroll
            for (int nt = 0; nt < 4; ++nt)
                bw[nt] = *(const bf16x8*)&Bs[cur * BSZ + (wn + nt * 16 + l16) * 64 + kk + quad * 8];
#pragma unroll
            for (int mt = 0; mt < MT; ++mt)
#pragma unroll
                for (int nt = 0; nt < 4; ++nt) acc[mt][nt] = MFMA16(af[mt], bw[nt], acc[mt][nt]);
        }
        cur ^= 1;
    }

#pragma unroll
    for (int mt = 0; mt < MT; ++mt)
#pragma unroll
        for (int nt = 0; nt < 4; ++nt) {
            int n = n0 + wn + nt * 16 + l16;
            float bv = bias ? bias[n] : 0.f;
#pragma unroll
            for (int r = 0; r < 4; ++r) {
                int m = m0 + wm + mt * 16 + quad * 4 + r;
                float v = acc[mt][nt][r] + bv;
                if constexpr (EPI == 2) v = gelu_tanh(v);
                if constexpr (EPI == 0 || EPI == 2) {
                    ((bf16_t*)Out)[(size_t)m * ldc + n] = (bf16_t)v;
                } else if constexpr (EPI == 1) {
                    ((float*)Out)[(size_t)m * ldc + n] = v + res[(size_t)m * ldc + n];
                } else { // EPI 4: qkv split
                    int b = m >> 11, t = m & 2047;
                    if (n < 2048) {
                        int h = (n & 1023) >> 6, d = n & 63;
                        bf16_t* dst = (n < 1024) ? (bf16_t*)Out : (bf16_t*)Out2;
                        dst[(((size_t)b * kH + h) * kT + t) * kD + d] = (bf16_t)v;
                    } else {
                        int n2 = n - 2048;
                        int h = n2 >> 6, d = n2 & 63;
                        ((bf16_t*)Out3)[(((size_t)b * kH + h) * kD + d) * kT + t] = (bf16_t)v;
                    }
                }
            }
        }
}

// ---------------- flash causal self-attention v4: dbuf K/V + XOR-swizzled LDS ----------------
// q,k: [b,h,t,d] bf16; vT: [b,h,d,t] bf16; sa out: [b,t,c] bf16
__global__ __launch_bounds__(256) void flash_self4(const bf16_t* __restrict__ qb, const bf16_t* __restrict__ kb,
                                                   const bf16_t* __restrict__ vT, bf16_t* __restrict__ sa) {
    const int tid = threadIdx.x;
    const int qi = gridDim.x - 1 - blockIdx.x; // heavy blocks first
    const int h = blockIdx.y, b = blockIdx.z;
    const int lane = tid & 63, wid = tid >> 6;
    const int l16 = lane & 15, quad = lane >> 4;
    const size_t bh = (size_t)b * kH + h;
    constexpr int TSZ = 64 * 64;

    __shared__ __align__(16) bf16_t Qs[TSZ];
    __shared__ __align__(16) bf16_t Ks[2 * TSZ];
    __shared__ __align__(16) bf16_t VTs[2 * TSZ];
    bf16_t* Ps = Qs; // reuse after Q frags are hoisted

    const bf16_t* qsrc = qb + (bh * kT + (size_t)qi * 64) * kD;
    const bf16_t* kbase = kb + bh * kT * kD;
    const bf16_t* vbase = vT + bh * kD * kT;

    // stage Q (pre-swizzled source, linear LDS dest)
#pragma unroll
    for (int i = 0; i < 2; ++i) {
        int chunk = tid + i * 256;
        int row = chunk >> 3, c8 = chunk & 7;
        gld_lds16(qsrc + row * 64 + ((c8 ^ (row & 7)) << 3), Qs + chunk * 8);
    }

    auto stageKV = [&](int buf, int kt) {
        const bf16_t* ksrc = kbase + (size_t)kt * 64 * kD;
        const bf16_t* vsrc = vbase + (size_t)kt * 64;
#pragma unroll
        for (int i = 0; i < 2; ++i) {
            int chunk = tid + i * 256;
            int row = chunk >> 3, c8 = chunk & 7;
            int sc = (c8 ^ (row & 7)) << 3;
            gld_lds16(ksrc + row * 64 + sc, Ks + buf * TSZ + chunk * 8);
            gld_lds16(vsrc + (size_t)row * kT + sc, VTs + buf * TSZ + chunk * 8);
        }
    };
    stageKV(0, 0);

    __syncthreads();
    bf16x8 aq[2];
    aq[0] = *(const bf16x8*)&Qs[swz(wid * 16 + l16, quad)];
    aq[1] = *(const bf16x8*)&Qs[swz(wid * 16 + l16, 4 + quad)];
#pragma unroll
    for (int j = 0; j < 8; ++j) { aq[0][j] *= (bf16_t)0.125f; aq[1][j] *= (bf16_t)0.125f; } // exact pow2

    f32x4 o[4] = {};
    float lsum[4] = {0.f, 0.f, 0.f, 0.f};
    const int qrow = qi * 64 + wid * 16 + quad * 4;
    int cur = 0;

    for (int kt = 0; kt <= qi; ++kt) {
        if (kt) __syncthreads();  // drains prefetched loads for buf `cur`; guards overwrite of other buf
        if (kt < qi) stageKV(cur ^ 1, kt + 1);

        f32x4 sf[4] = {};
#pragma unroll
        for (int kk = 0; kk < 2; ++kk)
#pragma unroll
            for (int nt = 0; nt < 4; ++nt) {
                bf16x8 bk = *(const bf16x8*)&Ks[cur * TSZ + swz(nt * 16 + l16, kk * 4 + quad)];
                sf[nt] = MFMA16(aq[kk], bk, sf[nt]);
            }

        const bool diag = (kt == qi);
#pragma unroll
        for (int nt = 0; nt < 4; ++nt) {
            int col = kt * 64 + nt * 16 + l16;
#pragma unroll
            for (int r = 0; r < 4; ++r) {
                float s = sf[nt][r];
                if (diag && col > qrow + r) s = -1e30f;
                float p = __expf(s);
                lsum[r] += p;
                int rp = wid * 16 + quad * 4 + r;
                int cc = nt * 16 + l16;
                Ps[rp * 64 + (cc ^ ((rp & 7) << 3))] = (bf16_t)p;
            }
        }
#pragma unroll
        for (int kk = 0; kk < 2; ++kk) {
            bf16x8 ap = *(const bf16x8*)&Ps[swz(wid * 16 + l16, kk * 4 + quad)];
#pragma unroll
            for (int dt = 0; dt < 4; ++dt) {
                bf16x8 bv = *(const bf16x8*)&VTs[cur * TSZ + swz(dt * 16 + l16, kk * 4 + quad)];
                o[dt] = MFMA16(ap, bv, o[dt]);
            }
        }
        cur ^= 1;
    }

#pragma unroll
    for (int r = 0; r < 4; ++r) {
        float s = lsum[r];
#pragma unroll
        for (int off = 1; off < 16; off <<= 1) s += __shfl_xor(s, off, 16);
        float inv = 1.f / s;
        size_t row = (size_t)b * kT + qi * 64 + wid * 16 + quad * 4 + r;
#pragma unroll
        for (int dt = 0; dt < 4; ++dt)
            sa[row * kC + h * kD + dt * 16 + l16] = (bf16_t)(o[dt][r] * inv);
    }
}

// ---------------- fused cross-attn v2: dbuf K/V + XOR-swizzled LDS ----------------
// q2: [b,t,c] bf16; k2: [b,s,c] bf16; v2T: [b,h,d,s] bf16
// ca out: [b,t,c] bf16; probs out: [b,h,t,s] fp32
__global__ __launch_bounds__(256) void ca_fused(const bf16_t* __restrict__ q2, const bf16_t* __restrict__ k2,
                                                const bf16_t* __restrict__ v2T, bf16_t* __restrict__ ca,
                                                float* __restrict__ probs) {
    const int tid = threadIdx.x;
    const int qi = blockIdx.x, z = blockIdx.y;
    const int b = z >> 4, h = z & 15;
    const int lane = tid & 63, wid = tid >> 6;
    const int l16 = lane & 15, quad = lane >> 4;
    const size_t bh = (size_t)z;
    constexpr int TSZ = 64 * 64;

    __shared__ __align__(16) bf16_t Qs[TSZ];
    __shared__ __align__(16) bf16_t Ks[2 * TSZ];
    __shared__ __align__(16) bf16_t VTs[2 * TSZ];
    bf16_t* Ps = Qs;

#pragma unroll
    for (int i = 0; i < 2; ++i) {
        int chunk = tid + i * 256;
        int row = chunk >> 3, c8 = chunk & 7;
        gld_lds16(q2 + ((size_t)(b * kT + qi * 64 + row)) * kC + h * kD + ((c8 ^ (row & 7)) << 3),
                  Qs + chunk * 8);
    }

    auto stageKV = [&](int buf, int kt) {
#pragma unroll
        for (int i = 0; i < 2; ++i) {
            int chunk = tid + i * 256;
            int row = chunk >> 3, c8 = chunk & 7;
            int sc = (c8 ^ (row & 7)) << 3;
            gld_lds16(k2 + ((size_t)(b * kS + kt * 64 + row)) * kC + h * kD + sc, Ks + buf * TSZ + chunk * 8);
            gld_lds16(v2T + (bh * kD + row) * kS + kt * 64 + sc, VTs + buf * TSZ + chunk * 8);
        }
    };
    stageKV(0, 0);

    __syncthreads();
    bf16x8 aq[2];
    aq[0] = *(const bf16x8*)&Qs[swz(wid * 16 + l16, quad)];
    aq[1] = *(const bf16x8*)&Qs[swz(wid * 16 + l16, 4 + quad)];
#pragma unroll
    for (int j = 0; j < 8; ++j) { aq[0][j] *= (bf16_t)0.125f; aq[1][j] *= (bf16_t)0.125f; }

    f32x4 o[4] = {};
    float lsum[4] = {0.f, 0.f, 0.f, 0.f};
    bf16x4 pk[9][4]; // packed P for final probs write (72 VGPRs)
    int cur = 0;

#pragma unroll
    for (int kt = 0; kt < 9; ++kt) {
        if (kt) __syncthreads();
        if (kt < 8) stageKV(cur ^ 1, kt + 1);

        f32x4 sf[4] = {};
#pragma unroll
        for (int kk = 0; kk < 2; ++kk)
#pragma unroll
            for (int nt = 0; nt < 4; ++nt) {
                bf16x8 bk = *(const bf16x8*)&Ks[cur * TSZ + swz(nt * 16 + l16, kk * 4 + quad)];
                sf[nt] = MFMA16(aq[kk], bk, sf[nt]);
            }
#pragma unroll
        for (int nt = 0; nt < 4; ++nt) {
            bf16x4 pc;
#pragma unroll
            for (int r = 0; r < 4; ++r) {
                float p = __expf(sf[nt][r]);
                lsum[r] += p;
                bf16_t pb = (bf16_t)p;
                pc[r] = pb;
                int rp = wid * 16 + quad * 4 + r;
                int cc = nt * 16 + l16;
                Ps[rp * 64 + (cc ^ ((rp & 7) << 3))] = pb;
            }
            pk[kt][nt] = pc;
        }
#pragma unroll
        for (int kk = 0; kk < 2; ++kk) {
            bf16x8 ap = *(const bf16x8*)&Ps[swz(wid * 16 + l16, kk * 4 + quad)];
#pragma unroll
            for (int dt = 0; dt < 4; ++dt) {
                bf16x8 bv = *(const bf16x8*)&VTs[cur * TSZ + swz(dt * 16 + l16, kk * 4 + quad)];
                o[dt] = MFMA16(ap, bv, o[dt]);
            }
        }
        cur ^= 1;
    }

    float inv[4];
#pragma unroll
    for (int r = 0; r < 4; ++r) {
        float s = lsum[r];
#pragma unroll
        for (int off = 1; off < 16; off <<= 1) s += __shfl_xor(s, off, 16);
        inv[r] = 1.f / s;
        size_t row = (size_t)b * kT + qi * 64 + wid * 16 + quad * 4 + r;
#pragma unroll
        for (int dt = 0; dt < 4; ++dt)
            ca[row * kC + h * kD + dt * 16 + l16] = (bf16_t)(o[dt][r] * inv[r]);
    }
    // probs = p * inv  (fp32, [b,h,t,s])
#pragma unroll
    for (int r = 0; r < 4; ++r) {
        float* dst = probs + ((size_t)z * kT + qi * 64 + wid * 16 + quad * 4 + r) * kS;
#pragma unroll
        for (int kt = 0; kt < 9; ++kt)
#pragma unroll
            for (int nt = 0; nt < 4; ++nt)
                dst[kt * 64 + nt * 16 + l16] = (float)pk[kt][nt][r] * inv[r];
    }
}

// ---------------- v2 [B,S,C] -> v2T [B,H,D,S] ----------------
__global__ void v_transpose(const bf16_t* __restrict__ v2, bf16_t* __restrict__ v2T) {
    int idx = blockIdx.x * 256 + threadIdx.x;
    int s = idx % kS;
    int t = idx / kS;
    int d = t % kD; t /= kD;
    int h = t % kH;
    int b = t / kH;
    v2T[idx] = v2[((size_t)(b * kS + s)) * kC + h * kD + d];
}

extern "C" void kernel_launch(void* const* d_in, const int* in_sizes, int n_in, void* d_out, int out_size,
                              void* d_ws, size_t ws_size, hipStream_t stream) {
    const float* x = (const float*)d_in[0];
    const float* context = (const float*)d_in[1];
    const float* ln1_w = (const float*)d_in[2];
    const float* ln1_b = (const float*)d_in[3];
    const float* ln2_w = (const float*)d_in[4];
    const float* ln2_b = (const float*)d_in[5];
    const float* ln3_w = (const float*)d_in[6];
    const float* ln3_b = (const float*)d_in[7];
    const float* attn_wqkv = (const float*)d_in[8];
    const float* attn_bqkv = (const float*)d_in[9];
    const float* attn_wproj = (const float*)d_in[10];
    const float* attn_bproj = (const float*)d_in[11];
    const float* ca_wq = (const float*)d_in[12];
    const float* ca_bq = (const float*)d_in[13];
    const float* ca_wk = (const float*)d_in[14];
    const float* ca_bk = (const float*)d_in[15];
    const float* ca_wv = (const float*)d_in[16];
    const float* ca_bv = (const float*)d_in[17];
    const float* ca_wproj = (const float*)d_in[18];
    const float* ca_bproj = (const float*)d_in[19];
    const float* fc_w = (const float*)d_in[20];
    const float* fc_b = (const float*)d_in[21];
    const float* proj_w = (const float*)d_in[22];
    const float* proj_b = (const float*)d_in[23];

    float* out_x = (float*)d_out;
    float* probs = out_x + (size_t)kB * kT * kC;

    char* wsp = (char*)d_ws;
    size_t off = 0;
    auto alloc = [&](size_t bytes) -> void* {
        void* p = wsp + off;
        off += (bytes + 255) & ~(size_t)255;
        return p;
    };
    bf16_t* wT_qkv   = (bf16_t*)alloc((size_t)3 * kC * kC * 2);
    bf16_t* wT_aproj = (bf16_t*)alloc((size_t)kC * kC * 2);
    bf16_t* wT_caq   = (bf16_t*)alloc((size_t)kC * kC * 2);
    bf16_t* wT_cak   = (bf16_t*)alloc((size_t)kC * kC * 2);
    bf16_t* wT_cav   = (bf16_t*)alloc((size_t)kC * kC * 2);
    bf16_t* wT_caproj= (bf16_t*)alloc((size_t)kC * kC * 2);
    bf16_t* wT_fc    = (bf16_t*)alloc((size_t)4 * kC * kC * 2);
    bf16_t* wT_proj  = (bf16_t*)alloc((size_t)4 * kC * kC * 2);
    bf16_t* hbuf     = (bf16_t*)alloc((size_t)kB * kT * kC * 2);
    bf16_t* qb       = (bf16_t*)alloc((size_t)kB * kT * kC * 2);
    bf16_t* kbuf     = (bf16_t*)alloc((size_t)kB * kT * kC * 2);
    bf16_t* vTb      = (bf16_t*)alloc((size_t)kB * kT * kC * 2);
    bf16_t* sabuf    = (bf16_t*)alloc((size_t)kB * kT * kC * 2);
    float*  x1       = (float*)alloc((size_t)kB * kT * kC * 4);
    float*  x2       = (float*)alloc((size_t)kB * kT * kC * 4);
    bf16_t* ctxb     = (bf16_t*)alloc((size_t)kB * kS * kC * 2);
    bf16_t* q2       = (bf16_t*)alloc((size_t)kB * kT * kC * 2);
    bf16_t* k2       = (bf16_t*)alloc((size_t)kB * kS * kC * 2);
    bf16_t* v2       = (bf16_t*)alloc((size_t)kB * kS * kC * 2);
    bf16_t* v2T      = (bf16_t*)alloc((size_t)kB * kS * kC * 2);
    bf16_t* hf       = (bf16_t*)alloc((size_t)kB * kT * 4 * kC * 2);
    (void)ws_size;

    dim3 tb(32, 8);
    transpose_w<<<dim3(96, 32), tb, 0, stream>>>(attn_wqkv, wT_qkv, kC, 3 * kC);
    transpose_w<<<dim3(32, 32), tb, 0, stream>>>(attn_wproj, wT_aproj, kC, kC);
    transpose_w<<<dim3(32, 32), tb, 0, stream>>>(ca_wq, wT_caq, kC, kC);
    transpose_w<<<dim3(32, 32), tb, 0, stream>>>(ca_wk, wT_cak, kC, kC);
    transpose_w<<<dim3(32, 32), tb, 0, stream>>>(ca_wv, wT_cav, kC, kC);
    transpose_w<<<dim3(32, 32), tb, 0, stream>>>(ca_wproj, wT_caproj, kC, kC);
    transpose_w<<<dim3(128, 32), tb, 0, stream>>>(fc_w, wT_fc, kC, 4 * kC);
    transpose_w<<<dim3(32, 128), tb, 0, stream>>>(proj_w, wT_proj, 4 * kC, kC);
    f32_to_bf16<<<dim3((kB * kS * kC / 4 + 255) / 256), 256, 0, stream>>>(context, ctxb, kB * kS * kC / 4);

    const int Mtok = kB * kT;   // 4096
    // LN1 -> hbuf
    ln_kernel<<<Mtok, 256, 0, stream>>>(x, ln1_w, ln1_b, hbuf);
    // qkv split -> qb [b,h,t,d], kbuf [b,h,t,d], vTb [b,h,d,t]
    gemm128<4, 128><<<dim3(24, 32), 256, 0, stream>>>(hbuf, wT_qkv, attn_bqkv, nullptr, qb, kbuf, vTb, Mtok,
                                                      3 * kC, kC, kC, kC, 0);
    // flash self-attn (no-max, dbuf+swizzle)
    flash_self4<<<dim3(kT / 64, kH, kB), 256, 0, stream>>>(qb, kbuf, vTb, sabuf);
    // x1 = x + sa @ Wproj + b
    gemm128<1, 64><<<dim3(8, 64), 256, 0, stream>>>(sabuf, wT_aproj, attn_bproj, x, x1, nullptr, nullptr, Mtok,
                                                    kC, kC, kC, kC, kC);
    // LN2 -> hbuf
    ln_kernel<<<Mtok, 256, 0, stream>>>(x1, ln2_w, ln2_b, hbuf);
    // q2 = h @ Wq + b
    gemm128<0, 64><<<dim3(8, 64), 256, 0, stream>>>(hbuf, wT_caq, ca_bq, nullptr, q2, nullptr, nullptr, Mtok, kC,
                                                    kC, kC, kC, kC);
    // k2 / v2 from context
    gemm128<0, 64><<<dim3(8, 18), 256, 0, stream>>>(ctxb, wT_cak, ca_bk, nullptr, k2, nullptr, nullptr, kB * kS,
                                                    kC, kC, kC, kC, kC);
    gemm128<0, 64><<<dim3(8, 18), 256, 0, stream>>>(ctxb, wT_cav, ca_bv, nullptr, v2, nullptr, nullptr, kB * kS,
                                                    kC, kC, kC, kC, kC);
    v_transpose<<<dim3(kB * kH * kD * kS / 256), 256, 0, stream>>>(v2, v2T);
    // fused cross-attn: scores + softmax + PV -> sabuf (ca), probs (d_out)
    ca_fused<<<dim3(kT / 64, kB * kH), 256, 0, stream>>>(q2, k2, v2T, sabuf, probs);
    // x2 = x1 + ca @ Wcaproj + b
    gemm128<1, 64><<<dim3(8, 64), 256, 0, stream>>>(sabuf, wT_caproj, ca_bproj, x1, x2, nullptr, nullptr, Mtok,
                                                    kC, kC, kC, kC, kC);
    // LN3 -> hbuf
    ln_kernel<<<Mtok, 256, 0, stream>>>(x2, ln3_w, ln3_b, hbuf);
    // hf = gelu(h @ fc_w + b)
    gemm128<2, 128><<<dim3(32, 32), 256, 0, stream>>>(hbuf, wT_fc, fc_b, nullptr, hf, nullptr, nullptr, Mtok,
                                                      4 * kC, kC, kC, kC, 4 * kC);
    // out = x2 + hf @ proj_w + b
    gemm128<1, 64><<<dim3(8, 64), 256, 0, stream>>>(hf, wT_proj, proj_b, x2, out_x, nullptr, nullptr, Mtok, kC,
                                                    4 * kC, 4 * kC, 4 * kC, kC);
}

// Round 5
// 706.754 us; speedup vs baseline: 1.1653x; 1.0789x over previous
//
#include <hip/hip_runtime.h>

typedef __bf16 bf16_t;
typedef __attribute__((ext_vector_type(8))) __bf16 bf16x8;
typedef __attribute__((ext_vector_type(4))) __bf16 bf16x4;
typedef __attribute__((ext_vector_type(4))) float f32x4;

static constexpr int kB = 2, kT = 2048, kS = 576, kC = 1024, kH = 16, kD = 64;

#define MFMA16(a, b, c) __builtin_amdgcn_mfma_f32_16x16x32_bf16((a), (b), (c), 0, 0, 0)

__device__ __forceinline__ void gld_lds16(const bf16_t* g, bf16_t* l) {
    __builtin_amdgcn_global_load_lds((const __attribute__((address_space(1))) unsigned int*)g,
                                     (__attribute__((address_space(3))) unsigned int*)l, 16, 0, 0);
}

// swizzled read offset (elements) for a [64-col] bf16 LDS tile staged with
// pre-swizzled global source: logical 16B-unit column q of `row` lives at q^(row&7).
__device__ __forceinline__ int swz(int row, int q) { return row * 64 + (((q ^ (row & 7)) & 7) << 3); }

__device__ inline float gelu_tanh(float x) {
    float u = 1.5957691216057308f * (x + 0.044715f * x * x * x);
    float t = 1.f - 2.f / (__expf(u) + 1.f);
    return 0.5f * x * (1.f + t);
}

// ---------------- weight transpose + f32->bf16: W[K,N] -> WT[N,K] ----------------
__global__ void transpose_w(const float* __restrict__ W, bf16_t* __restrict__ WT, int K, int N) {
    __shared__ float tile[32][33];
    int n0 = blockIdx.x * 32, k0 = blockIdx.y * 32;
    int tx = threadIdx.x, ty = threadIdx.y;
#pragma unroll
    for (int i = 0; i < 4; ++i)
        tile[ty + i * 8][tx] = W[(size_t)(k0 + ty + i * 8) * N + n0 + tx];
    __syncthreads();
#pragma unroll
    for (int i = 0; i < 4; ++i)
        WT[(size_t)(n0 + ty + i * 8) * K + k0 + tx] = (bf16_t)tile[tx][ty + i * 8];
}

// ---------------- f32 -> bf16 elementwise (n4 = count/4) ----------------
__global__ void f32_to_bf16(const float* __restrict__ in, bf16_t* __restrict__ out, int n4) {
    int i = blockIdx.x * 256 + threadIdx.x;
    if (i < n4) {
        float4 v = ((const float4*)in)[i];
        bf16x4 o;
        o[0] = (bf16_t)v.x; o[1] = (bf16_t)v.y; o[2] = (bf16_t)v.z; o[3] = (bf16_t)v.w;
        ((bf16x4*)out)[i] = o;
    }
}

// ---------------- LayerNorm: fp32 in [rows, 1024] -> bf16 out ----------------
__global__ __launch_bounds__(256) void ln_kernel(const float* __restrict__ x,
                                                 const float* __restrict__ w,
                                                 const float* __restrict__ bb,
                                                 bf16_t* __restrict__ out) {
    int row = blockIdx.x, tid = threadIdx.x;
    const float* xr = x + (size_t)row * kC;
    float4 v = ((const float4*)xr)[tid];
    float s1 = v.x + v.y + v.z + v.w;
    float s2 = v.x * v.x + v.y * v.y + v.z * v.z + v.w * v.w;
#pragma unroll
    for (int o = 32; o > 0; o >>= 1) {
        s1 += __shfl_down(s1, o);
        s2 += __shfl_down(s2, o);
    }
    __shared__ float red[8];
    __shared__ float mv[2];
    int wid = tid >> 6, lane = tid & 63;
    if (lane == 0) { red[wid] = s1; red[4 + wid] = s2; }
    __syncthreads();
    if (tid == 0) {
        float a = red[0] + red[1] + red[2] + red[3];
        float c = red[4] + red[5] + red[6] + red[7];
        float mean = a * (1.f / kC);
        float var = c * (1.f / kC) - mean * mean;
        mv[0] = mean;
        mv[1] = rsqrtf(var + 1e-5f);
    }
    __syncthreads();
    float mean = mv[0], rstd = mv[1];
    float4 wv = ((const float4*)w)[tid];
    float4 bv = ((const float4*)bb)[tid];
    bf16x4 o4;
    o4[0] = (bf16_t)((v.x - mean) * rstd * wv.x + bv.x);
    o4[1] = (bf16_t)((v.y - mean) * rstd * wv.y + bv.y);
    o4[2] = (bf16_t)((v.z - mean) * rstd * wv.z + bv.z);
    o4[3] = (bf16_t)((v.w - mean) * rstd * wv.w + bv.w);
    *(bf16x4*)&out[(size_t)row * kC + tid * 4] = o4;
}

#define VWAIT(n) asm volatile("s_waitcnt vmcnt(" #n ")" ::: "memory")
#define CFENCE() asm volatile("" ::: "memory")

// ---------------- pipelined GEMM: C[M,N] = A[M,K] @ WT[N,K]^T (+epilogue) ----------------
// DEPTH=2, counted-vmcnt raw-barrier pipeline (T4) + XOR-swizzled LDS (T2).
// LDS: BM=64 -> 48KB, BM=128 -> 64KB (static limit respected).
// EPI: 0 bf16+bias, 1 f32 = acc+bias+res, 2 bf16 gelu(acc+bias), 4 qkv-split (Out=q,Out2=k,Out3=vT)
template <int EPI, int BM>
__global__ __launch_bounds__(256) void gemm128(const bf16_t* __restrict__ A, const bf16_t* __restrict__ Bw,
                                               const float* __restrict__ bias, const float* __restrict__ res,
                                               void* __restrict__ Out, void* __restrict__ Out2,
                                               void* __restrict__ Out3, int M, int N, int K, int lda, int ldb,
                                               int ldc) {
    constexpr int MT = BM / 32;
    constexpr int ASZ = BM * 64, BSZ = 128 * 64;
    __shared__ __align__(16) bf16_t As[2 * ASZ];
    __shared__ __align__(16) bf16_t Bs[2 * BSZ];
    const int tid = threadIdx.x;
    const int m0 = blockIdx.y * BM, n0 = blockIdx.x * 128;
    const int lane = tid & 63, wid = tid >> 6;
    const int l16 = lane & 15, quad = lane >> 4;
    const int wm = (wid >> 1) * (BM / 2), wn = (wid & 1) * 64;
    f32x4 acc[MT][4] = {};

    const bf16_t* Ab = A + (size_t)m0 * lda;
    const bf16_t* Bb = Bw + (size_t)n0 * ldb;

    auto stage = [&](int buf, int k0) {
#pragma unroll
        for (int i = 0; i < BM / 32; ++i) {
            int chunk = tid + i * 256;
            int row = chunk >> 3, c8 = chunk & 7;
            gld_lds16(Ab + (size_t)row * lda + k0 + ((c8 ^ (row & 7)) << 3), As + buf * ASZ + chunk * 8);
        }
#pragma unroll
        for (int i = 0; i < 4; ++i) {
            int chunk = tid + i * 256;
            int row = chunk >> 3, c8 = chunk & 7;
            gld_lds16(Bb + (size_t)row * ldb + k0 + ((c8 ^ (row & 7)) << 3), Bs + buf * BSZ + chunk * 8);
        }
    };

    const int nk = K / 64;
    stage(0, 0);
    int cur = 0;
    for (int t = 0; t < nk; ++t) {
        __builtin_amdgcn_s_barrier();  // all waves done reading the buffer about to be overwritten
        CFENCE();
        if (t + 1 < nk) {
            stage(cur ^ 1, (t + 1) * 64);
            // wait for tile t's loads (oldest); keep tile t+1's in flight across the barrier
            if constexpr (BM == 64) VWAIT(6); else VWAIT(8);
        } else {
            VWAIT(0);
        }
        __builtin_amdgcn_s_barrier();  // every wave's tile-t loads have landed
        CFENCE();
#pragma unroll
        for (int kk = 0; kk < 2; ++kk) {
            bf16x8 af[MT], bw[4];
#pragma unroll
            for (int mt = 0; mt < MT; ++mt)
                af[mt] = *(const bf16x8*)&As[cur * ASZ + swz(wm + mt * 16 + l16, kk * 4 + quad)];
#pragma unroll
            for (int nt = 0; nt < 4; ++nt)
                bw[nt] = *(const bf16x8*)&Bs[cur * BSZ + swz(wn + nt * 16 + l16, kk * 4 + quad)];
#pragma unroll
            for (int mt = 0; mt < MT; ++mt)
#pragma unroll
                for (int nt = 0; nt < 4; ++nt) acc[mt][nt] = MFMA16(af[mt], bw[nt], acc[mt][nt]);
        }
        cur ^= 1;
    }

#pragma unroll
    for (int mt = 0; mt < MT; ++mt)
#pragma unroll
        for (int nt = 0; nt < 4; ++nt) {
            int n = n0 + wn + nt * 16 + l16;
            float bv = bias ? bias[n] : 0.f;
#pragma unroll
            for (int r = 0; r < 4; ++r) {
                int m = m0 + wm + mt * 16 + quad * 4 + r;
                float v = acc[mt][nt][r] + bv;
                if constexpr (EPI == 2) v = gelu_tanh(v);
                if constexpr (EPI == 0 || EPI == 2) {
                    ((bf16_t*)Out)[(size_t)m * ldc + n] = (bf16_t)v;
                } else if constexpr (EPI == 1) {
                    ((float*)Out)[(size_t)m * ldc + n] = v + res[(size_t)m * ldc + n];
                } else { // EPI 4: qkv split
                    int b = m >> 11, t = m & 2047;
                    if (n < 2048) {
                        int h = (n & 1023) >> 6, d = n & 63;
                        bf16_t* dst = (n < 1024) ? (bf16_t*)Out : (bf16_t*)Out2;
                        dst[(((size_t)b * kH + h) * kT + t) * kD + d] = (bf16_t)v;
                    } else {
                        int n2 = n - 2048;
                        int h = n2 >> 6, d = n2 & 63;
                        ((bf16_t*)Out3)[(((size_t)b * kH + h) * kD + d) * kT + t] = (bf16_t)v;
                    }
                }
            }
        }
}

// ---------------- flash causal self-attention v4: dbuf K/V + XOR-swizzled LDS ----------------
// q,k: [b,h,t,d] bf16; vT: [b,h,d,t] bf16; sa out: [b,t,c] bf16
__global__ __launch_bounds__(256) void flash_self4(const bf16_t* __restrict__ qb, const bf16_t* __restrict__ kb,
                                                   const bf16_t* __restrict__ vT, bf16_t* __restrict__ sa) {
    const int tid = threadIdx.x;
    const int qi = gridDim.x - 1 - blockIdx.x; // heavy blocks first
    const int h = blockIdx.y, b = blockIdx.z;
    const int lane = tid & 63, wid = tid >> 6;
    const int l16 = lane & 15, quad = lane >> 4;
    const size_t bh = (size_t)b * kH + h;
    constexpr int TSZ = 64 * 64;

    __shared__ __align__(16) bf16_t Qs[TSZ];
    __shared__ __align__(16) bf16_t Ks[2 * TSZ];
    __shared__ __align__(16) bf16_t VTs[2 * TSZ];
    bf16_t* Ps = Qs; // reuse after Q frags are hoisted

    const bf16_t* qsrc = qb + (bh * kT + (size_t)qi * 64) * kD;
    const bf16_t* kbase = kb + bh * kT * kD;
    const bf16_t* vbase = vT + bh * kD * kT;

    // stage Q (pre-swizzled source, linear LDS dest)
#pragma unroll
    for (int i = 0; i < 2; ++i) {
        int chunk = tid + i * 256;
        int row = chunk >> 3, c8 = chunk & 7;
        gld_lds16(qsrc + row * 64 + ((c8 ^ (row & 7)) << 3), Qs + chunk * 8);
    }

    auto stageKV = [&](int buf, int kt) {
        const bf16_t* ksrc = kbase + (size_t)kt * 64 * kD;
        const bf16_t* vsrc = vbase + (size_t)kt * 64;
#pragma unroll
        for (int i = 0; i < 2; ++i) {
            int chunk = tid + i * 256;
            int row = chunk >> 3, c8 = chunk & 7;
            int sc = (c8 ^ (row & 7)) << 3;
            gld_lds16(ksrc + row * 64 + sc, Ks + buf * TSZ + chunk * 8);
            gld_lds16(vsrc + (size_t)row * kT + sc, VTs + buf * TSZ + chunk * 8);
        }
    };
    stageKV(0, 0);

    __syncthreads();
    bf16x8 aq[2];
    aq[0] = *(const bf16x8*)&Qs[swz(wid * 16 + l16, quad)];
    aq[1] = *(const bf16x8*)&Qs[swz(wid * 16 + l16, 4 + quad)];
#pragma unroll
    for (int j = 0; j < 8; ++j) { aq[0][j] *= (bf16_t)0.125f; aq[1][j] *= (bf16_t)0.125f; } // exact pow2

    f32x4 o[4] = {};
    float lsum[4] = {0.f, 0.f, 0.f, 0.f};
    const int qrow = qi * 64 + wid * 16 + quad * 4;
    int cur = 0;

    for (int kt = 0; kt <= qi; ++kt) {
        if (kt) __syncthreads();  // drains prefetched loads for buf `cur`; guards overwrite of other buf
        if (kt < qi) stageKV(cur ^ 1, kt + 1);

        f32x4 sf[4] = {};
#pragma unroll
        for (int kk = 0; kk < 2; ++kk)
#pragma unroll
            for (int nt = 0; nt < 4; ++nt) {
                bf16x8 bk = *(const bf16x8*)&Ks[cur * TSZ + swz(nt * 16 + l16, kk * 4 + quad)];
                sf[nt] = MFMA16(aq[kk], bk, sf[nt]);
            }

        const bool diag = (kt == qi);
#pragma unroll
        for (int nt = 0; nt < 4; ++nt) {
            int col = kt * 64 + nt * 16 + l16;
#pragma unroll
            for (int r = 0; r < 4; ++r) {
                float s = sf[nt][r];
                if (diag && col > qrow + r) s = -1e30f;
                float p = __expf(s);
                lsum[r] += p;
                int rp = wid * 16 + quad * 4 + r;
                int cc = nt * 16 + l16;
                Ps[rp * 64 + (cc ^ ((rp & 7) << 3))] = (bf16_t)p;
            }
        }
#pragma unroll
        for (int kk = 0; kk < 2; ++kk) {
            bf16x8 ap = *(const bf16x8*)&Ps[swz(wid * 16 + l16, kk * 4 + quad)];
#pragma unroll
            for (int dt = 0; dt < 4; ++dt) {
                bf16x8 bv = *(const bf16x8*)&VTs[cur * TSZ + swz(dt * 16 + l16, kk * 4 + quad)];
                o[dt] = MFMA16(ap, bv, o[dt]);
            }
        }
        cur ^= 1;
    }

#pragma unroll
    for (int r = 0; r < 4; ++r) {
        float s = lsum[r];
#pragma unroll
        for (int off = 1; off < 16; off <<= 1) s += __shfl_xor(s, off, 16);
        float inv = 1.f / s;
        size_t row = (size_t)b * kT + qi * 64 + wid * 16 + quad * 4 + r;
#pragma unroll
        for (int dt = 0; dt < 4; ++dt)
            sa[row * kC + h * kD + dt * 16 + l16] = (bf16_t)(o[dt][r] * inv);
    }
}

// ---------------- fused cross-attn v2: dbuf K/V + XOR-swizzled LDS ----------------
// q2: [b,t,c] bf16; k2: [b,s,c] bf16; v2T: [b,h,d,s] bf16
// ca out: [b,t,c] bf16; probs out: [b,h,t,s] fp32
__global__ __launch_bounds__(256) void ca_fused(const bf16_t* __restrict__ q2, const bf16_t* __restrict__ k2,
                                                const bf16_t* __restrict__ v2T, bf16_t* __restrict__ ca,
                                                float* __restrict__ probs) {
    const int tid = threadIdx.x;
    const int qi = blockIdx.x, z = blockIdx.y;
    const int b = z >> 4, h = z & 15;
    const int lane = tid & 63, wid = tid >> 6;
    const int l16 = lane & 15, quad = lane >> 4;
    const size_t bh = (size_t)z;
    constexpr int TSZ = 64 * 64;

    __shared__ __align__(16) bf16_t Qs[TSZ];
    __shared__ __align__(16) bf16_t Ks[2 * TSZ];
    __shared__ __align__(16) bf16_t VTs[2 * TSZ];
    bf16_t* Ps = Qs;

#pragma unroll
    for (int i = 0; i < 2; ++i) {
        int chunk = tid + i * 256;
        int row = chunk >> 3, c8 = chunk & 7;
        gld_lds16(q2 + ((size_t)(b * kT + qi * 64 + row)) * kC + h * kD + ((c8 ^ (row & 7)) << 3),
                  Qs + chunk * 8);
    }

    auto stageKV = [&](int buf, int kt) {
#pragma unroll
        for (int i = 0; i < 2; ++i) {
            int chunk = tid + i * 256;
            int row = chunk >> 3, c8 = chunk & 7;
            int sc = (c8 ^ (row & 7)) << 3;
            gld_lds16(k2 + ((size_t)(b * kS + kt * 64 + row)) * kC + h * kD + sc, Ks + buf * TSZ + chunk * 8);
            gld_lds16(v2T + (bh * kD + row) * kS + kt * 64 + sc, VTs + buf * TSZ + chunk * 8);
        }
    };
    stageKV(0, 0);

    __syncthreads();
    bf16x8 aq[2];
    aq[0] = *(const bf16x8*)&Qs[swz(wid * 16 + l16, quad)];
    aq[1] = *(const bf16x8*)&Qs[swz(wid * 16 + l16, 4 + quad)];
#pragma unroll
    for (int j = 0; j < 8; ++j) { aq[0][j] *= (bf16_t)0.125f; aq[1][j] *= (bf16_t)0.125f; }

    f32x4 o[4] = {};
    float lsum[4] = {0.f, 0.f, 0.f, 0.f};
    bf16x4 pk[9][4]; // packed P for final probs write (72 VGPRs)
    int cur = 0;

#pragma unroll
    for (int kt = 0; kt < 9; ++kt) {
        if (kt) __syncthreads();
        if (kt < 8) stageKV(cur ^ 1, kt + 1);

        f32x4 sf[4] = {};
#pragma unroll
        for (int kk = 0; kk < 2; ++kk)
#pragma unroll
            for (int nt = 0; nt < 4; ++nt) {
                bf16x8 bk = *(const bf16x8*)&Ks[cur * TSZ + swz(nt * 16 + l16, kk * 4 + quad)];
                sf[nt] = MFMA16(aq[kk], bk, sf[nt]);
            }
#pragma unroll
        for (int nt = 0; nt < 4; ++nt) {
            bf16x4 pc;
#pragma unroll
            for (int r = 0; r < 4; ++r) {
                float p = __expf(sf[nt][r]);
                lsum[r] += p;
                bf16_t pb = (bf16_t)p;
                pc[r] = pb;
                int rp = wid * 16 + quad * 4 + r;
                int cc = nt * 16 + l16;
                Ps[rp * 64 + (cc ^ ((rp & 7) << 3))] = pb;
            }
            pk[kt][nt] = pc;
        }
#pragma unroll
        for (int kk = 0; kk < 2; ++kk) {
            bf16x8 ap = *(const bf16x8*)&Ps[swz(wid * 16 + l16, kk * 4 + quad)];
#pragma unroll
            for (int dt = 0; dt < 4; ++dt) {
                bf16x8 bv = *(const bf16x8*)&VTs[cur * TSZ + swz(dt * 16 + l16, kk * 4 + quad)];
                o[dt] = MFMA16(ap, bv, o[dt]);
            }
        }
        cur ^= 1;
    }

    float inv[4];
#pragma unroll
    for (int r = 0; r < 4; ++r) {
        float s = lsum[r];
#pragma unroll
        for (int off = 1; off < 16; off <<= 1) s += __shfl_xor(s, off, 16);
        inv[r] = 1.f / s;
        size_t row = (size_t)b * kT + qi * 64 + wid * 16 + quad * 4 + r;
#pragma unroll
        for (int dt = 0; dt < 4; ++dt)
            ca[row * kC + h * kD + dt * 16 + l16] = (bf16_t)(o[dt][r] * inv[r]);
    }
    // probs = p * inv  (fp32, [b,h,t,s])
#pragma unroll
    for (int r = 0; r < 4; ++r) {
        float* dst = probs + ((size_t)z * kT + qi * 64 + wid * 16 + quad * 4 + r) * kS;
#pragma unroll
        for (int kt = 0; kt < 9; ++kt)
#pragma unroll
            for (int nt = 0; nt < 4; ++nt)
                dst[kt * 64 + nt * 16 + l16] = (float)pk[kt][nt][r] * inv[r];
    }
}

// ---------------- v2 [B,S,C] -> v2T [B,H,D,S] ----------------
__global__ void v_transpose(const bf16_t* __restrict__ v2, bf16_t* __restrict__ v2T) {
    int idx = blockIdx.x * 256 + threadIdx.x;
    int s = idx % kS;
    int t = idx / kS;
    int d = t % kD; t /= kD;
    int h = t % kH;
    int b = t / kH;
    v2T[idx] = v2[((size_t)(b * kS + s)) * kC + h * kD + d];
}

extern "C" void kernel_launch(void* const* d_in, const int* in_sizes, int n_in, void* d_out, int out_size,
                              void* d_ws, size_t ws_size, hipStream_t stream) {
    const float* x = (const float*)d_in[0];
    const float* context = (const float*)d_in[1];
    const float* ln1_w = (const float*)d_in[2];
    const float* ln1_b = (const float*)d_in[3];
    const float* ln2_w = (const float*)d_in[4];
    const float* ln2_b = (const float*)d_in[5];
    const float* ln3_w = (const float*)d_in[6];
    const float* ln3_b = (const float*)d_in[7];
    const float* attn_wqkv = (const float*)d_in[8];
    const float* attn_bqkv = (const float*)d_in[9];
    const float* attn_wproj = (const float*)d_in[10];
    const float* attn_bproj = (const float*)d_in[11];
    const float* ca_wq = (const float*)d_in[12];
    const float* ca_bq = (const float*)d_in[13];
    const float* ca_wk = (const float*)d_in[14];
    const float* ca_bk = (const float*)d_in[15];
    const float* ca_wv = (const float*)d_in[16];
    const float* ca_bv = (const float*)d_in[17];
    const float* ca_wproj = (const float*)d_in[18];
    const float* ca_bproj = (const float*)d_in[19];
    const float* fc_w = (const float*)d_in[20];
    const float* fc_b = (const float*)d_in[21];
    const float* proj_w = (const float*)d_in[22];
    const float* proj_b = (const float*)d_in[23];

    float* out_x = (float*)d_out;
    float* probs = out_x + (size_t)kB * kT * kC;

    char* wsp = (char*)d_ws;
    size_t off = 0;
    auto alloc = [&](size_t bytes) -> void* {
        void* p = wsp + off;
        off += (bytes + 255) & ~(size_t)255;
        return p;
    };
    bf16_t* wT_qkv   = (bf16_t*)alloc((size_t)3 * kC * kC * 2);
    bf16_t* wT_aproj = (bf16_t*)alloc((size_t)kC * kC * 2);
    bf16_t* wT_caq   = (bf16_t*)alloc((size_t)kC * kC * 2);
    bf16_t* wT_cak   = (bf16_t*)alloc((size_t)kC * kC * 2);
    bf16_t* wT_cav   = (bf16_t*)alloc((size_t)kC * kC * 2);
    bf16_t* wT_caproj= (bf16_t*)alloc((size_t)kC * kC * 2);
    bf16_t* wT_fc    = (bf16_t*)alloc((size_t)4 * kC * kC * 2);
    bf16_t* wT_proj  = (bf16_t*)alloc((size_t)4 * kC * kC * 2);
    bf16_t* hbuf     = (bf16_t*)alloc((size_t)kB * kT * kC * 2);
    bf16_t* qb       = (bf16_t*)alloc((size_t)kB * kT * kC * 2);
    bf16_t* kbuf     = (bf16_t*)alloc((size_t)kB * kT * kC * 2);
    bf16_t* vTb      = (bf16_t*)alloc((size_t)kB * kT * kC * 2);
    bf16_t* sabuf    = (bf16_t*)alloc((size_t)kB * kT * kC * 2);
    float*  x1       = (float*)alloc((size_t)kB * kT * kC * 4);
    float*  x2       = (float*)alloc((size_t)kB * kT * kC * 4);
    bf16_t* ctxb     = (bf16_t*)alloc((size_t)kB * kS * kC * 2);
    bf16_t* q2       = (bf16_t*)alloc((size_t)kB * kT * kC * 2);
    bf16_t* k2       = (bf16_t*)alloc((size_t)kB * kS * kC * 2);
    bf16_t* v2       = (bf16_t*)alloc((size_t)kB * kS * kC * 2);
    bf16_t* v2T      = (bf16_t*)alloc((size_t)kB * kS * kC * 2);
    bf16_t* hf       = (bf16_t*)alloc((size_t)kB * kT * 4 * kC * 2);
    (void)ws_size;

    dim3 tb(32, 8);
    transpose_w<<<dim3(96, 32), tb, 0, stream>>>(attn_wqkv, wT_qkv, kC, 3 * kC);
    transpose_w<<<dim3(32, 32), tb, 0, stream>>>(attn_wproj, wT_aproj, kC, kC);
    transpose_w<<<dim3(32, 32), tb, 0, stream>>>(ca_wq, wT_caq, kC, kC);
    transpose_w<<<dim3(32, 32), tb, 0, stream>>>(ca_wk, wT_cak, kC, kC);
    transpose_w<<<dim3(32, 32), tb, 0, stream>>>(ca_wv, wT_cav, kC, kC);
    transpose_w<<<dim3(32, 32), tb, 0, stream>>>(ca_wproj, wT_caproj, kC, kC);
    transpose_w<<<dim3(128, 32), tb, 0, stream>>>(fc_w, wT_fc, kC, 4 * kC);
    transpose_w<<<dim3(32, 128), tb, 0, stream>>>(proj_w, wT_proj, 4 * kC, kC);
    f32_to_bf16<<<dim3((kB * kS * kC / 4 + 255) / 256), 256, 0, stream>>>(context, ctxb, kB * kS * kC / 4);

    const int Mtok = kB * kT;   // 4096
    // LN1 -> hbuf
    ln_kernel<<<Mtok, 256, 0, stream>>>(x, ln1_w, ln1_b, hbuf);
    // qkv split -> qb [b,h,t,d], kbuf [b,h,t,d], vTb [b,h,d,t]
    gemm128<4, 128><<<dim3(24, 32), 256, 0, stream>>>(hbuf, wT_qkv, attn_bqkv, nullptr, qb, kbuf, vTb, Mtok,
                                                      3 * kC, kC, kC, kC, 0);
    // flash self-attn (no-max, dbuf+swizzle)
    flash_self4<<<dim3(kT / 64, kH, kB), 256, 0, stream>>>(qb, kbuf, vTb, sabuf);
    // x1 = x + sa @ Wproj + b
    gemm128<1, 64><<<dim3(8, 64), 256, 0, stream>>>(sabuf, wT_aproj, attn_bproj, x, x1, nullptr, nullptr, Mtok,
                                                    kC, kC, kC, kC, kC);
    // LN2 -> hbuf
    ln_kernel<<<Mtok, 256, 0, stream>>>(x1, ln2_w, ln2_b, hbuf);
    // q2 = h @ Wq + b
    gemm128<0, 64><<<dim3(8, 64), 256, 0, stream>>>(hbuf, wT_caq, ca_bq, nullptr, q2, nullptr, nullptr, Mtok, kC,
                                                    kC, kC, kC, kC);
    // k2 / v2 from context
    gemm128<0, 64><<<dim3(8, 18), 256, 0, stream>>>(ctxb, wT_cak, ca_bk, nullptr, k2, nullptr, nullptr, kB * kS,
                                                    kC, kC, kC, kC, kC);
    gemm128<0, 64><<<dim3(8, 18), 256, 0, stream>>>(ctxb, wT_cav, ca_bv, nullptr, v2, nullptr, nullptr, kB * kS,
                                                    kC, kC, kC, kC, kC);
    v_transpose<<<dim3(kB * kH * kD * kS / 256), 256, 0, stream>>>(v2, v2T);
    // fused cross-attn: scores + softmax + PV -> sabuf (ca), probs (d_out)
    ca_fused<<<dim3(kT / 64, kB * kH), 256, 0, stream>>>(q2, k2, v2T, sabuf, probs);
    // x2 = x1 + ca @ Wcaproj + b
    gemm128<1, 64><<<dim3(8, 64), 256, 0, stream>>>(sabuf, wT_caproj, ca_bproj, x1, x2, nullptr, nullptr, Mtok,
                                                    kC, kC, kC, kC, kC);
    // LN3 -> hbuf
    ln_kernel<<<Mtok, 256, 0, stream>>>(x2, ln3_w, ln3_b, hbuf);
    // hf = gelu(h @ fc_w + b)
    gemm128<2, 128><<<dim3(32, 32), 256, 0, stream>>>(hbuf, wT_fc, fc_b, nullptr, hf, nullptr, nullptr, Mtok,
                                                      4 * kC, kC, kC, kC, 4 * kC);
    // out = x2 + hf @ proj_w + b
    gemm128<1, 64><<<dim3(8, 64), 256, 0, stream>>>(hf, wT_proj, proj_b, x2, out_x, nullptr, nullptr, Mtok, kC,
                                                    4 * kC, 4 * kC, 4 * kC, kC);
}

// Round 6
// 682.106 us; speedup vs baseline: 1.2075x; 1.0361x over previous
//
#include <hip/hip_runtime.h>

typedef __bf16 bf16_t;
typedef __attribute__((ext_vector_type(8))) __bf16 bf16x8;
typedef __attribute__((ext_vector_type(4))) __bf16 bf16x4;
typedef __attribute__((ext_vector_type(4))) float f32x4;

static constexpr int kB = 2, kT = 2048, kS = 576, kC = 1024, kH = 16, kD = 64;

#define MFMA16(a, b, c) __builtin_amdgcn_mfma_f32_16x16x32_bf16((a), (b), (c), 0, 0, 0)

__device__ __forceinline__ void gld_lds16(const bf16_t* g, bf16_t* l) {
    __builtin_amdgcn_global_load_lds((const __attribute__((address_space(1))) unsigned int*)g,
                                     (__attribute__((address_space(3))) unsigned int*)l, 16, 0, 0);
}

// swizzled read offset (elements) for a [64-col] bf16 LDS tile staged with
// pre-swizzled global source: logical 16B-unit column q of `row` lives at q^(row&7).
__device__ __forceinline__ int swz(int row, int q) { return row * 64 + (((q ^ (row & 7)) & 7) << 3); }

__device__ inline float gelu_tanh(float x) {
    float u = 1.5957691216057308f * (x + 0.044715f * x * x * x);
    float t = 1.f - 2.f / (__expf(u) + 1.f);
    return 0.5f * x * (1.f + t);
}

#define VWAIT(n) asm volatile("s_waitcnt vmcnt(" #n ")" ::: "memory")
#define CFENCE() asm volatile("" ::: "memory")

// ---------------- batched prep: 8 weight transposes (f32->bf16, W[K,N]->WT[N,K]) + ctx cast ----------------
__device__ __forceinline__ void do_tr(float (*tile)[33], const float* __restrict__ W, bf16_t* __restrict__ WT,
                                      int K, int N, int t, int nx, int tid) {
    int n0 = (t % nx) * 32, k0 = (t / nx) * 32;
    int tx = tid & 31, ty = tid >> 5;
#pragma unroll
    for (int i = 0; i < 4; ++i)
        tile[ty + i * 8][tx] = W[(size_t)(k0 + ty + i * 8) * N + n0 + tx];
    __syncthreads();
#pragma unroll
    for (int i = 0; i < 4; ++i)
        WT[(size_t)(n0 + ty + i * 8) * K + k0 + tx] = (bf16_t)tile[tx][ty + i * 8];
}

__global__ __launch_bounds__(256) void batch_prep(const float* __restrict__ w_qkv, const float* __restrict__ w_aproj,
                                                  const float* __restrict__ w_caq, const float* __restrict__ w_cak,
                                                  const float* __restrict__ w_cav, const float* __restrict__ w_caproj,
                                                  const float* __restrict__ w_fc, const float* __restrict__ w_proj,
                                                  const float* __restrict__ ctx,
                                                  bf16_t* __restrict__ wT_qkv, bf16_t* __restrict__ wT_aproj,
                                                  bf16_t* __restrict__ wT_caq, bf16_t* __restrict__ wT_cakv,
                                                  bf16_t* __restrict__ wT_caproj, bf16_t* __restrict__ wT_fc,
                                                  bf16_t* __restrict__ wT_proj, bf16_t* __restrict__ ctxb) {
    __shared__ float tile[32][33];
    int bid = blockIdx.x, tid = threadIdx.x;
    if (bid < 3072)        do_tr(tile, w_qkv, wT_qkv, 1024, 3072, bid, 96, tid);
    else if (bid < 4096)   do_tr(tile, w_aproj, wT_aproj, 1024, 1024, bid - 3072, 32, tid);
    else if (bid < 5120)   do_tr(tile, w_caq, wT_caq, 1024, 1024, bid - 4096, 32, tid);
    else if (bid < 6144)   do_tr(tile, w_cak, wT_cakv, 1024, 1024, bid - 5120, 32, tid);
    else if (bid < 7168)   do_tr(tile, w_cav, wT_cakv + (size_t)1024 * 1024, 1024, 1024, bid - 6144, 32, tid);
    else if (bid < 8192)   do_tr(tile, w_caproj, wT_caproj, 1024, 1024, bid - 7168, 32, tid);
    else if (bid < 12288)  do_tr(tile, w_fc, wT_fc, 1024, 4096, bid - 8192, 128, tid);
    else if (bid < 16384)  do_tr(tile, w_proj, wT_proj, 4096, 1024, bid - 12288, 32, tid);
    else {
        int i = (bid - 16384) * 256 + tid;
        const int n4 = kB * kS * kC / 4;
        if (i < n4) {
            float4 v = ((const float4*)ctx)[i];
            bf16x4 o;
            o[0] = (bf16_t)v.x; o[1] = (bf16_t)v.y; o[2] = (bf16_t)v.z; o[3] = (bf16_t)v.w;
            ((bf16x4*)ctxb)[i] = o;
        }
    }
}

// ---------------- LayerNorm: fp32 in [rows, 1024] -> bf16 out ----------------
__global__ __launch_bounds__(256) void ln_kernel(const float* __restrict__ x,
                                                 const float* __restrict__ w,
                                                 const float* __restrict__ bb,
                                                 bf16_t* __restrict__ out) {
    int row = blockIdx.x, tid = threadIdx.x;
    const float* xr = x + (size_t)row * kC;
    float4 v = ((const float4*)xr)[tid];
    float s1 = v.x + v.y + v.z + v.w;
    float s2 = v.x * v.x + v.y * v.y + v.z * v.z + v.w * v.w;
#pragma unroll
    for (int o = 32; o > 0; o >>= 1) {
        s1 += __shfl_down(s1, o);
        s2 += __shfl_down(s2, o);
    }
    __shared__ float red[8];
    __shared__ float mv[2];
    int wid = tid >> 6, lane = tid & 63;
    if (lane == 0) { red[wid] = s1; red[4 + wid] = s2; }
    __syncthreads();
    if (tid == 0) {
        float a = red[0] + red[1] + red[2] + red[3];
        float c = red[4] + red[5] + red[6] + red[7];
        float mean = a * (1.f / kC);
        float var = c * (1.f / kC) - mean * mean;
        mv[0] = mean;
        mv[1] = rsqrtf(var + 1e-5f);
    }
    __syncthreads();
    float mean = mv[0], rstd = mv[1];
    float4 wv = ((const float4*)w)[tid];
    float4 bv = ((const float4*)bb)[tid];
    bf16x4 o4;
    o4[0] = (bf16_t)((v.x - mean) * rstd * wv.x + bv.x);
    o4[1] = (bf16_t)((v.y - mean) * rstd * wv.y + bv.y);
    o4[2] = (bf16_t)((v.z - mean) * rstd * wv.z + bv.z);
    o4[3] = (bf16_t)((v.w - mean) * rstd * wv.w + bv.w);
    *(bf16x4*)&out[(size_t)row * kC + tid * 4] = o4;
}

// ---------------- pipelined GEMM: C[M,N] = A[M,K] @ WT[N,K]^T (+epilogue) ----------------
// DEPTH=2 counted-vmcnt raw-barrier pipeline (T4) + XOR-swizzled LDS (T2) + XCD swizzle (T1) + setprio (T5).
// EPI: 0 bf16+bias, 1 f32 = acc+bias+res, 2 bf16 gelu(acc+bias), 4 qkv-split, 5 k/vT-split (res=2nd bias)
template <int EPI, int BM>
__global__ __launch_bounds__(256) void gemm128(const bf16_t* __restrict__ A, const bf16_t* __restrict__ Bw,
                                               const float* __restrict__ bias, const float* __restrict__ res,
                                               void* __restrict__ Out, void* __restrict__ Out2,
                                               void* __restrict__ Out3, int M, int N, int K, int lda, int ldb,
                                               int ldc) {
    constexpr int MT = BM / 32;
    constexpr int ASZ = BM * 64, BSZ = 128 * 64;
    __shared__ __align__(16) bf16_t As[2 * ASZ];
    __shared__ __align__(16) bf16_t Bs[2 * BSZ];
    const int tid = threadIdx.x;
    // XCD-aware chunked swizzle (all grids have nwg % 8 == 0)
    const int nwg = gridDim.x * gridDim.y;
    const int orig = blockIdx.y * gridDim.x + blockIdx.x;
    const int wg = (orig & 7) * (nwg >> 3) + (orig >> 3);
    const int m0 = (wg / gridDim.x) * BM, n0 = (wg % gridDim.x) * 128;
    const int lane = tid & 63, wid = tid >> 6;
    const int l16 = lane & 15, quad = lane >> 4;
    const int wm = (wid >> 1) * (BM / 2), wn = (wid & 1) * 64;
    f32x4 acc[MT][4] = {};

    const bf16_t* Ab = A + (size_t)m0 * lda;
    const bf16_t* Bb = Bw + (size_t)n0 * ldb;

    auto stage = [&](int buf, int k0) {
#pragma unroll
        for (int i = 0; i < BM / 32; ++i) {
            int chunk = tid + i * 256;
            int row = chunk >> 3, c8 = chunk & 7;
            gld_lds16(Ab + (size_t)row * lda + k0 + ((c8 ^ (row & 7)) << 3), As + buf * ASZ + chunk * 8);
        }
#pragma unroll
        for (int i = 0; i < 4; ++i) {
            int chunk = tid + i * 256;
            int row = chunk >> 3, c8 = chunk & 7;
            gld_lds16(Bb + (size_t)row * ldb + k0 + ((c8 ^ (row & 7)) << 3), Bs + buf * BSZ + chunk * 8);
        }
    };

    const int nk = K / 64;
    stage(0, 0);
    int cur = 0;
    for (int t = 0; t < nk; ++t) {
        __builtin_amdgcn_s_barrier();  // all waves done reading the buffer about to be overwritten
        CFENCE();
        if (t + 1 < nk) {
            stage(cur ^ 1, (t + 1) * 64);
            if constexpr (BM == 64) VWAIT(6); else VWAIT(8);
        } else {
            VWAIT(0);
        }
        __builtin_amdgcn_s_barrier();  // every wave's tile-t loads have landed
        CFENCE();
        __builtin_amdgcn_s_setprio(1);
#pragma unroll
        for (int kk = 0; kk < 2; ++kk) {
            bf16x8 af[MT], bw[4];
#pragma unroll
            for (int mt = 0; mt < MT; ++mt)
                af[mt] = *(const bf16x8*)&As[cur * ASZ + swz(wm + mt * 16 + l16, kk * 4 + quad)];
#pragma unroll
            for (int nt = 0; nt < 4; ++nt)
                bw[nt] = *(const bf16x8*)&Bs[cur * BSZ + swz(wn + nt * 16 + l16, kk * 4 + quad)];
#pragma unroll
            for (int mt = 0; mt < MT; ++mt)
#pragma unroll
                for (int nt = 0; nt < 4; ++nt) acc[mt][nt] = MFMA16(af[mt], bw[nt], acc[mt][nt]);
        }
        __builtin_amdgcn_s_setprio(0);
        cur ^= 1;
    }

#pragma unroll
    for (int mt = 0; mt < MT; ++mt)
#pragma unroll
        for (int nt = 0; nt < 4; ++nt) {
            int n = n0 + wn + nt * 16 + l16;
            float bv;
            if constexpr (EPI == 5) bv = (n < kC) ? bias[n] : res[n - kC];
            else bv = bias ? bias[n] : 0.f;
#pragma unroll
            for (int r = 0; r < 4; ++r) {
                int m = m0 + wm + mt * 16 + quad * 4 + r;
                float v = acc[mt][nt][r] + bv;
                if constexpr (EPI == 2) v = gelu_tanh(v);
                if constexpr (EPI == 0 || EPI == 2) {
                    ((bf16_t*)Out)[(size_t)m * ldc + n] = (bf16_t)v;
                } else if constexpr (EPI == 1) {
                    ((float*)Out)[(size_t)m * ldc + n] = v + res[(size_t)m * ldc + n];
                } else if constexpr (EPI == 5) {  // k2 [b,s,c] / v2T [b,h,d,s]
                    int b2 = (m >= kS) ? 1 : 0;
                    int s2 = m - b2 * kS;
                    if (n < kC) {
                        ((bf16_t*)Out)[(size_t)m * kC + n] = (bf16_t)v;
                    } else {
                        int n2 = n - kC, hh = n2 >> 6, d = n2 & 63;
                        ((bf16_t*)Out2)[(((size_t)b2 * kH + hh) * kD + d) * kS + s2] = (bf16_t)v;
                    }
                } else { // EPI 4: qkv split
                    int b = m >> 11, t = m & 2047;
                    if (n < 2048) {
                        int h = (n & 1023) >> 6, d = n & 63;
                        bf16_t* dst = (n < 1024) ? (bf16_t*)Out : (bf16_t*)Out2;
                        dst[(((size_t)b * kH + h) * kT + t) * kD + d] = (bf16_t)v;
                    } else {
                        int n2 = n - 2048;
                        int h = n2 >> 6, d = n2 & 63;
                        ((bf16_t*)Out3)[(((size_t)b * kH + h) * kD + d) * kT + t] = (bf16_t)v;
                    }
                }
            }
        }
}

// ---------------- flash causal self-attention v5: QBLK=128, counted-vmcnt pipeline, swizzled LDS ----------------
// q,k: [b,h,t,d] bf16; vT: [b,h,d,t] bf16; sa out: [b,t,c] bf16
__global__ __launch_bounds__(256) void flash_self5(const bf16_t* __restrict__ qb, const bf16_t* __restrict__ kb,
                                                   const bf16_t* __restrict__ vT, bf16_t* __restrict__ sa) {
    const int tid = threadIdx.x;
    const int qi = gridDim.x - 1 - blockIdx.x; // heavy blocks first
    const int h = blockIdx.y, b = blockIdx.z;
    const int lane = tid & 63, wid = tid >> 6;
    const int l16 = lane & 15, quad = lane >> 4;
    const size_t bh = (size_t)b * kH + h;
    constexpr int TSZ = 64 * 64;

    __shared__ __align__(16) bf16_t Qs[2 * TSZ];  // 128x64 Q; reused as Ps[2] after frag hoist
    __shared__ __align__(16) bf16_t Ks[2 * TSZ];
    __shared__ __align__(16) bf16_t VTs[2 * TSZ];
    bf16_t* Ps = Qs;

    const bf16_t* qsrc = qb + (bh * kT + (size_t)qi * 128) * kD;
    const bf16_t* kbase = kb + bh * kT * kD;
    const bf16_t* vbase = vT + bh * kD * kT;

    // stage Q (128 rows; pre-swizzled source, linear LDS dest)
#pragma unroll
    for (int i = 0; i < 4; ++i) {
        int chunk = tid + i * 256;
        int row = chunk >> 3, c8 = chunk & 7;
        gld_lds16(qsrc + row * 64 + ((c8 ^ (row & 7)) << 3), Qs + chunk * 8);
    }

    auto stageKV = [&](int buf, int kt2) {
        const bf16_t* ksrc = kbase + (size_t)kt2 * 64 * kD;
        const bf16_t* vsrc = vbase + (size_t)kt2 * 64;
#pragma unroll
        for (int i = 0; i < 2; ++i) {
            int chunk = tid + i * 256;
            int row = chunk >> 3, c8 = chunk & 7;
            int sc = (c8 ^ (row & 7)) << 3;
            gld_lds16(ksrc + row * 64 + sc, Ks + buf * TSZ + chunk * 8);
            gld_lds16(vsrc + (size_t)row * kT + sc, VTs + buf * TSZ + chunk * 8);
        }
    };
    stageKV(0, 0);
    VWAIT(4);                      // this wave's Q loads landed; tile-0 K/V may stay in flight
    __builtin_amdgcn_s_barrier();  // all waves' Q in LDS
    CFENCE();

    bf16x8 aq[2][2];
#pragma unroll
    for (int u = 0; u < 2; ++u) {
        int row = u * 64 + wid * 16 + l16;
        aq[u][0] = *(const bf16x8*)&Qs[swz(row, quad)];
        aq[u][1] = *(const bf16x8*)&Qs[swz(row, 4 + quad)];
#pragma unroll
        for (int j = 0; j < 8; ++j) { aq[u][0][j] *= (bf16_t)0.125f; aq[u][1][j] *= (bf16_t)0.125f; }
    }

    f32x4 o[2][4] = {};
    float lsum[2][4] = {};
    int cur = 0;
    const int nkt = 2 * qi + 2;

    for (int kt = 0; kt < nkt; ++kt) {
        __builtin_amdgcn_s_barrier();  // readers of overwrite-target buffer (and Q hoist at kt==0) done
        CFENCE();
        if (kt + 1 < nkt) { stageKV(cur ^ 1, kt + 1); VWAIT(4); }
        else VWAIT(0);
        __builtin_amdgcn_s_barrier();  // tile kt's K/V visible to all waves
        CFENCE();

        const bool skip0 = (kt == 2 * qi + 1);
#pragma unroll
        for (int u = 0; u < 2; ++u) {
            if (u == 0 && skip0) continue;  // fully-masked sub-tile
            f32x4 sf[4] = {};
#pragma unroll
            for (int kk = 0; kk < 2; ++kk)
#pragma unroll
                for (int nt = 0; nt < 4; ++nt) {
                    bf16x8 bk = *(const bf16x8*)&Ks[cur * TSZ + swz(nt * 16 + l16, kk * 4 + quad)];
                    sf[nt] = MFMA16(aq[u][kk], bk, sf[nt]);
                }
            const bool diag = (kt == 2 * qi + u);
            const int qrow = qi * 128 + u * 64 + wid * 16 + quad * 4;
#pragma unroll
            for (int nt = 0; nt < 4; ++nt) {
                int col = kt * 64 + nt * 16 + l16;
#pragma unroll
                for (int r = 0; r < 4; ++r) {
                    float s = sf[nt][r];
                    if (diag && col > qrow + r) s = -1e30f;
                    float p = __expf(s);
                    lsum[u][r] += p;
                    int rp = wid * 16 + quad * 4 + r;
                    int cc = nt * 16 + l16;
                    Ps[u * TSZ + rp * 64 + (cc ^ ((rp & 7) << 3))] = (bf16_t)p;
                }
            }
#pragma unroll
            for (int kk = 0; kk < 2; ++kk) {
                bf16x8 ap = *(const bf16x8*)&Ps[u * TSZ + swz(wid * 16 + l16, kk * 4 + quad)];
#pragma unroll
                for (int dt = 0; dt < 4; ++dt) {
                    bf16x8 bv = *(const bf16x8*)&VTs[cur * TSZ + swz(dt * 16 + l16, kk * 4 + quad)];
                    o[u][dt] = MFMA16(ap, bv, o[u][dt]);
                }
            }
        }
        cur ^= 1;
    }

#pragma unroll
    for (int u = 0; u < 2; ++u)
#pragma unroll
        for (int r = 0; r < 4; ++r) {
            float s = lsum[u][r];
#pragma unroll
            for (int off = 1; off < 16; off <<= 1) s += __shfl_xor(s, off, 16);
            float inv = 1.f / s;
            size_t row = (size_t)b * kT + qi * 128 + u * 64 + wid * 16 + quad * 4 + r;
#pragma unroll
            for (int dt = 0; dt < 4; ++dt)
                sa[row * kC + h * kD + dt * 16 + l16] = (bf16_t)(o[u][dt][r] * inv);
        }
}

// ---------------- fused cross-attn v3: counted-vmcnt pipeline + XOR-swizzled LDS ----------------
// q2: [b,t,c] bf16; k2: [b,s,c] bf16; v2T: [b,h,d,s] bf16
// ca out: [b,t,c] bf16; probs out: [b,h,t,s] fp32
__global__ __launch_bounds__(256) void ca_fused(const bf16_t* __restrict__ q2, const bf16_t* __restrict__ k2,
                                                const bf16_t* __restrict__ v2T, bf16_t* __restrict__ ca,
                                                float* __restrict__ probs) {
    const int tid = threadIdx.x;
    const int qi = blockIdx.x, z = blockIdx.y;
    const int b = z >> 4, h = z & 15;
    const int lane = tid & 63, wid = tid >> 6;
    const int l16 = lane & 15, quad = lane >> 4;
    const size_t bh = (size_t)z;
    constexpr int TSZ = 64 * 64;

    __shared__ __align__(16) bf16_t Qs[TSZ];
    __shared__ __align__(16) bf16_t Ks[2 * TSZ];
    __shared__ __align__(16) bf16_t VTs[2 * TSZ];
    bf16_t* Ps = Qs;

#pragma unroll
    for (int i = 0; i < 2; ++i) {
        int chunk = tid + i * 256;
        int row = chunk >> 3, c8 = chunk & 7;
        gld_lds16(q2 + ((size_t)(b * kT + qi * 64 + row)) * kC + h * kD + ((c8 ^ (row & 7)) << 3),
                  Qs + chunk * 8);
    }

    auto stageKV = [&](int buf, int kt) {
#pragma unroll
        for (int i = 0; i < 2; ++i) {
            int chunk = tid + i * 256;
            int row = chunk >> 3, c8 = chunk & 7;
            int sc = (c8 ^ (row & 7)) << 3;
            gld_lds16(k2 + ((size_t)(b * kS + kt * 64 + row)) * kC + h * kD + sc, Ks + buf * TSZ + chunk * 8);
            gld_lds16(v2T + (bh * kD + row) * kS + kt * 64 + sc, VTs + buf * TSZ + chunk * 8);
        }
    };
    stageKV(0, 0);
    VWAIT(4);                      // Q landed (per-wave); tile-0 K/V may stay in flight
    __builtin_amdgcn_s_barrier();
    CFENCE();

    bf16x8 aq[2];
    aq[0] = *(const bf16x8*)&Qs[swz(wid * 16 + l16, quad)];
    aq[1] = *(const bf16x8*)&Qs[swz(wid * 16 + l16, 4 + quad)];
#pragma unroll
    for (int j = 0; j < 8; ++j) { aq[0][j] *= (bf16_t)0.125f; aq[1][j] *= (bf16_t)0.125f; }

    f32x4 o[4] = {};
    float lsum[4] = {0.f, 0.f, 0.f, 0.f};
    bf16x4 pk[9][4]; // packed P for final probs write (72 VGPRs)
    int cur = 0;

#pragma unroll
    for (int kt = 0; kt < 9; ++kt) {
        __builtin_amdgcn_s_barrier();
        CFENCE();
        if (kt < 8) { stageKV(cur ^ 1, kt + 1); VWAIT(4); }
        else VWAIT(0);
        __builtin_amdgcn_s_barrier();
        CFENCE();

        f32x4 sf[4] = {};
#pragma unroll
        for (int kk = 0; kk < 2; ++kk)
#pragma unroll
            for (int nt = 0; nt < 4; ++nt) {
                bf16x8 bk = *(const bf16x8*)&Ks[cur * TSZ + swz(nt * 16 + l16, kk * 4 + quad)];
                sf[nt] = MFMA16(aq[kk], bk, sf[nt]);
            }
#pragma unroll
        for (int nt = 0; nt < 4; ++nt) {
            bf16x4 pc;
#pragma unroll
            for (int r = 0; r < 4; ++r) {
                float p = __expf(sf[nt][r]);
                lsum[r] += p;
                bf16_t pb = (bf16_t)p;
                pc[r] = pb;
                int rp = wid * 16 + quad * 4 + r;
                int cc = nt * 16 + l16;
                Ps[rp * 64 + (cc ^ ((rp & 7) << 3))] = pb;
            }
            pk[kt][nt] = pc;
        }
#pragma unroll
        for (int kk = 0; kk < 2; ++kk) {
            bf16x8 ap = *(const bf16x8*)&Ps[swz(wid * 16 + l16, kk * 4 + quad)];
#pragma unroll
            for (int dt = 0; dt < 4; ++dt) {
                bf16x8 bv = *(const bf16x8*)&VTs[cur * TSZ + swz(dt * 16 + l16, kk * 4 + quad)];
                o[dt] = MFMA16(ap, bv, o[dt]);
            }
        }
        cur ^= 1;
    }

    float inv[4];
#pragma unroll
    for (int r = 0; r < 4; ++r) {
        float s = lsum[r];
#pragma unroll
        for (int off = 1; off < 16; off <<= 1) s += __shfl_xor(s, off, 16);
        inv[r] = 1.f / s;
        size_t row = (size_t)b * kT + qi * 64 + wid * 16 + quad * 4 + r;
#pragma unroll
        for (int dt = 0; dt < 4; ++dt)
            ca[row * kC + h * kD + dt * 16 + l16] = (bf16_t)(o[dt][r] * inv[r]);
    }
    // probs = p * inv  (fp32, [b,h,t,s])
#pragma unroll
    for (int r = 0; r < 4; ++r) {
        float* dst = probs + ((size_t)z * kT + qi * 64 + wid * 16 + quad * 4 + r) * kS;
#pragma unroll
        for (int kt = 0; kt < 9; ++kt)
#pragma unroll
            for (int nt = 0; nt < 4; ++nt)
                dst[kt * 64 + nt * 16 + l16] = (float)pk[kt][nt][r] * inv[r];
    }
}

extern "C" void kernel_launch(void* const* d_in, const int* in_sizes, int n_in, void* d_out, int out_size,
                              void* d_ws, size_t ws_size, hipStream_t stream) {
    const float* x = (const float*)d_in[0];
    const float* context = (const float*)d_in[1];
    const float* ln1_w = (const float*)d_in[2];
    const float* ln1_b = (const float*)d_in[3];
    const float* ln2_w = (const float*)d_in[4];
    const float* ln2_b = (const float*)d_in[5];
    const float* ln3_w = (const float*)d_in[6];
    const float* ln3_b = (const float*)d_in[7];
    const float* attn_wqkv = (const float*)d_in[8];
    const float* attn_bqkv = (const float*)d_in[9];
    const float* attn_wproj = (const float*)d_in[10];
    const float* attn_bproj = (const float*)d_in[11];
    const float* ca_wq = (const float*)d_in[12];
    const float* ca_bq = (const float*)d_in[13];
    const float* ca_wk = (const float*)d_in[14];
    const float* ca_bk = (const float*)d_in[15];
    const float* ca_wv = (const float*)d_in[16];
    const float* ca_bv = (const float*)d_in[17];
    const float* ca_wproj = (const float*)d_in[18];
    const float* ca_bproj = (const float*)d_in[19];
    const float* fc_w = (const float*)d_in[20];
    const float* fc_b = (const float*)d_in[21];
    const float* proj_w = (const float*)d_in[22];
    const float* proj_b = (const float*)d_in[23];

    float* out_x = (float*)d_out;
    float* probs = out_x + (size_t)kB * kT * kC;

    char* wsp = (char*)d_ws;
    size_t off = 0;
    auto alloc = [&](size_t bytes) -> void* {
        void* p = wsp + off;
        off += (bytes + 255) & ~(size_t)255;
        return p;
    };
    bf16_t* wT_qkv   = (bf16_t*)alloc((size_t)3 * kC * kC * 2);
    bf16_t* wT_aproj = (bf16_t*)alloc((size_t)kC * kC * 2);
    bf16_t* wT_caq   = (bf16_t*)alloc((size_t)kC * kC * 2);
    bf16_t* wT_cakv  = (bf16_t*)alloc((size_t)2 * kC * kC * 2);
    bf16_t* wT_caproj= (bf16_t*)alloc((size_t)kC * kC * 2);
    bf16_t* wT_fc    = (bf16_t*)alloc((size_t)4 * kC * kC * 2);
    bf16_t* wT_proj  = (bf16_t*)alloc((size_t)4 * kC * kC * 2);
    bf16_t* hbuf     = (bf16_t*)alloc((size_t)kB * kT * kC * 2);
    bf16_t* qb       = (bf16_t*)alloc((size_t)kB * kT * kC * 2);
    bf16_t* kbuf     = (bf16_t*)alloc((size_t)kB * kT * kC * 2);
    bf16_t* vTb      = (bf16_t*)alloc((size_t)kB * kT * kC * 2);
    bf16_t* sabuf    = (bf16_t*)alloc((size_t)kB * kT * kC * 2);
    float*  x1       = (float*)alloc((size_t)kB * kT * kC * 4);
    float*  x2       = (float*)alloc((size_t)kB * kT * kC * 4);
    bf16_t* ctxb     = (bf16_t*)alloc((size_t)kB * kS * kC * 2);
    bf16_t* q2       = (bf16_t*)alloc((size_t)kB * kT * kC * 2);
    bf16_t* k2       = (bf16_t*)alloc((size_t)kB * kS * kC * 2);
    bf16_t* v2T      = (bf16_t*)alloc((size_t)kB * kS * kC * 2);
    bf16_t* hf       = (bf16_t*)alloc((size_t)kB * kT * 4 * kC * 2);
    (void)ws_size;

    // all weight transposes + ctx cast in one launch
    batch_prep<<<dim3(17536), 256, 0, stream>>>(attn_wqkv, attn_wproj, ca_wq, ca_wk, ca_wv, ca_wproj, fc_w,
                                                proj_w, context, wT_qkv, wT_aproj, wT_caq, wT_cakv, wT_caproj,
                                                wT_fc, wT_proj, ctxb);

    const int Mtok = kB * kT;   // 4096
    // LN1 -> hbuf
    ln_kernel<<<Mtok, 256, 0, stream>>>(x, ln1_w, ln1_b, hbuf);
    // qkv split -> qb [b,h,t,d], kbuf [b,h,t,d], vTb [b,h,d,t]
    gemm128<4, 128><<<dim3(24, 32), 256, 0, stream>>>(hbuf, wT_qkv, attn_bqkv, nullptr, qb, kbuf, vTb, Mtok,
                                                      3 * kC, kC, kC, kC, 0);
    // flash self-attn (QBLK=128, counted pipeline)
    flash_self5<<<dim3(kT / 128, kH, kB), 256, 0, stream>>>(qb, kbuf, vTb, sabuf);
    // x1 = x + sa @ Wproj + b
    gemm128<1, 64><<<dim3(8, 64), 256, 0, stream>>>(sabuf, wT_aproj, attn_bproj, x, x1, nullptr, nullptr, Mtok,
                                                    kC, kC, kC, kC, kC);
    // LN2 -> hbuf
    ln_kernel<<<Mtok, 256, 0, stream>>>(x1, ln2_w, ln2_b, hbuf);
    // q2 = h @ Wq + b
    gemm128<0, 64><<<dim3(8, 64), 256, 0, stream>>>(hbuf, wT_caq, ca_bq, nullptr, q2, nullptr, nullptr, Mtok, kC,
                                                    kC, kC, kC, kC);
    // k2 [b,s,c] + v2T [b,h,d,s] in one GEMM (EPI 5; res = second bias)
    gemm128<5, 64><<<dim3(16, 18), 256, 0, stream>>>(ctxb, wT_cakv, ca_bk, ca_bv, k2, v2T, nullptr, kB * kS,
                                                     2 * kC, kC, kC, kC, 0);
    // fused cross-attn: scores + softmax + PV -> sabuf (ca), probs (d_out)
    ca_fused<<<dim3(kT / 64, kB * kH), 256, 0, stream>>>(q2, k2, v2T, sabuf, probs);
    // x2 = x1 + ca @ Wcaproj + b
    gemm128<1, 64><<<dim3(8, 64), 256, 0, stream>>>(sabuf, wT_caproj, ca_bproj, x1, x2, nullptr, nullptr, Mtok,
                                                    kC, kC, kC, kC, kC);
    // LN3 -> hbuf
    ln_kernel<<<Mtok, 256, 0, stream>>>(x2, ln3_w, ln3_b, hbuf);
    // hf = gelu(h @ fc_w + b)
    gemm128<2, 128><<<dim3(32, 32), 256, 0, stream>>>(hbuf, wT_fc, fc_b, nullptr, hf, nullptr, nullptr, Mtok,
                                                      4 * kC, kC, kC, kC, 4 * kC);
    // out = x2 + hf @ proj_w + b
    gemm128<1, 64><<<dim3(8, 64), 256, 0, stream>>>(hf, wT_proj, proj_b, x2, out_x, nullptr, nullptr, Mtok, kC,
                                                    4 * kC, 4 * kC, 4 * kC, kC);
}